// Round 1
// baseline (829.342 us; speedup 1.0000x reference)
//
#include <hip/hip_runtime.h>
#include <math.h>

#define TPB 256

__device__ __forceinline__ float dot4(float4 a, float4 b){
  return a.x*b.x + a.y*b.y + a.z*b.z + a.w*b.w;
}

// ---------------------------------------------------------------------------
// Kernel A: per-sample fused classical frontend.
// One block (256 threads) per sample. All intermediates in LDS.
// Layouts are channel-contiguous [row][col][ch] so ic-chunks are aligned float4.
// Writes qin[b*4+w] = tanh(fc(feat))*pi to workspace.
// ---------------------------------------------------------------------------
__global__ __launch_bounds__(TPB) void classical_kernel(
    const float* __restrict__ xg,
    const float* __restrict__ w1g, const float* __restrict__ b1g,
    const float* __restrict__ w2g, const float* __restrict__ b2g,
    const float* __restrict__ w3g, const float* __restrict__ b3g,
    const float* __restrict__ fcwg, const float* __restrict__ fcbg,
    float* __restrict__ qin, int B)
{
  // padded input: rows 0..29 (y+1), cols padded to 32 for float4 sweeps
  __shared__ __align__(16) float xs[30*32];        // 960
  // conv1 out, padded [16][16][8]  (r=oy+1,c=ox+1)
  __shared__ __align__(16) float c1s[16*16*8];     // 2048
  // conv2+pool out, padded [9][9][16] (r=py+1,c=px+1)
  __shared__ __align__(16) float c2ps[9*9*16];     // 1296
  // conv3 out [7][7][16]
  __shared__ __align__(16) float c3s[7*7*16];      // 784
  __shared__ __align__(16) float w1s[72];          // [oc][k]
  __shared__ __align__(16) float w2s[16*9*8];      // [oc][k][ic]
  __shared__ __align__(16) float w3s[16*9*16];     // [oc][k][ic]
  __shared__ float b1s[8], b2s[16], b3s[16];
  __shared__ __align__(16) float feat[256];

  const int tid = threadIdx.x;
  const int b   = blockIdx.x;

  // ---- phase 0a: zero padded buffers + stage (reordered) weights ----
  for (int i=tid; i< 960; i+=TPB) xs[i]   = 0.f;
  for (int i=tid; i<2048; i+=TPB) c1s[i]  = 0.f;
  for (int i=tid; i<1296; i+=TPB) c2ps[i] = 0.f;
  for (int i=tid; i<72; i+=TPB) w1s[i] = w1g[i];      // (8,1,3,3) -> [oc][k]
  if (tid < 8)  b1s[tid] = b1g[tid];
  if (tid < 16) b2s[tid] = b2g[tid];
  if (tid < 16) b3s[tid] = b3g[tid];
  // conv2_w (16,8,3,3): dst [oc][k][ic]
  for (int i=tid; i<1152; i+=TPB){
    int oc=i/72, r=i%72, k=r/8, ic=r%8;
    w2s[i] = w2g[oc*72 + ic*9 + k];
  }
  // conv3_w (16,16,3,3): dst [oc][k][ic]
  for (int i=tid; i<2304; i+=TPB){
    int oc=i/144, r=i%144, k=r/16, ic=r%16;
    w3s[i] = w3g[oc*144 + ic*9 + k];
  }
  __syncthreads();

  // ---- phase 0b: fill padded input interior ----
  for (int i=tid; i<784; i+=TPB){
    int y=i/28, x=i%28;
    xs[(y+1)*32 + (x+1)] = xg[(size_t)b*784 + i];
  }
  __syncthreads();

  // ---- phase 1: conv1 (1->8, stride2, pad1) + relu ----
  // task = (oc, oy) row sweep; 112 tasks
  if (tid < 112){
    const int oc = tid / 14;
    const int oy = tid % 14;
    float acc[14];
    #pragma unroll
    for (int x=0;x<14;++x) acc[x] = b1s[oc];
    #pragma unroll
    for (int ky=0; ky<3; ++ky){
      float rv[32];
      #pragma unroll
      for (int c4=0;c4<8;++c4){
        float4 v = *(const float4*)&xs[(2*oy+ky)*32 + c4*4];
        rv[c4*4+0]=v.x; rv[c4*4+1]=v.y; rv[c4*4+2]=v.z; rv[c4*4+3]=v.w;
      }
      #pragma unroll
      for (int kx=0;kx<3;++kx){
        const float w = w1s[oc*9 + ky*3 + kx];
        #pragma unroll
        for (int x=0;x<14;++x) acc[x] += rv[2*x+kx] * w;
      }
    }
    #pragma unroll
    for (int x=0;x<14;++x)
      c1s[((oy+1)*16 + (x+1))*8 + oc] = fmaxf(acc[x], 0.f);
  }
  __syncthreads();

  // ---- phase 2: conv2 (8->16, pad1) + relu + maxpool2 ----
  // task = (py,px,oc); each computes the 2x2 pre-pool window; 784 tasks
  for (int tau=tid; tau<784; tau+=TPB){
    const int oc = tau & 15;
    const int s  = tau >> 4;          // 0..48
    const int py = s / 7, px = s % 7;
    const int r0 = 2*py, c0 = 2*px;   // padded coords: rows r0..r0+3
    float a00=0.f, a01=0.f, a10=0.f, a11=0.f;
    #pragma unroll
    for (int ch=0; ch<2; ++ch){       // ic chunks of 4
      float4 in[4][4];
      #pragma unroll
      for (int r=0;r<4;++r)
        #pragma unroll
        for (int c=0;c<4;++c)
          in[r][c] = *(const float4*)&c1s[((r0+r)*16 + (c0+c))*8 + ch*4];
      #pragma unroll
      for (int k=0;k<9;++k){
        const int ky=k/3, kx=k%3;
        const float4 w = *(const float4*)&w2s[(oc*9+k)*8 + ch*4];
        a00 += dot4(in[ky  ][kx  ], w);
        a01 += dot4(in[ky  ][kx+1], w);
        a10 += dot4(in[ky+1][kx  ], w);
        a11 += dot4(in[ky+1][kx+1], w);
      }
    }
    // relu(max+b) == max(relu(+b)) since relu monotone
    const float m = fmaxf(fmaxf(a00,a01), fmaxf(a10,a11)) + b2s[oc];
    c2ps[((py+1)*9 + (px+1))*16 + oc] = fmaxf(m, 0.f);
  }
  __syncthreads();

  // ---- phase 3: conv3 (16->16, pad1) + relu ----
  // task = (oc, y) row sweep; 112 tasks
  if (tid < 112){
    const int oc = tid / 7;
    const int y  = tid % 7;
    float acc[7] = {0.f,0.f,0.f,0.f,0.f,0.f,0.f};
    #pragma unroll
    for (int ch=0; ch<4; ++ch){       // ic chunks of 4
      #pragma unroll
      for (int ky=0; ky<3; ++ky){
        float4 row[9];
        #pragma unroll
        for (int c=0;c<9;++c)
          row[c] = *(const float4*)&c2ps[((y+ky)*9 + c)*16 + ch*4];
        const float4 wk0 = *(const float4*)&w3s[(oc*9+ky*3+0)*16 + ch*4];
        const float4 wk1 = *(const float4*)&w3s[(oc*9+ky*3+1)*16 + ch*4];
        const float4 wk2 = *(const float4*)&w3s[(oc*9+ky*3+2)*16 + ch*4];
        #pragma unroll
        for (int x=0;x<7;++x)
          acc[x] += dot4(row[x],wk0) + dot4(row[x+1],wk1) + dot4(row[x+2],wk2);
      }
    }
    #pragma unroll
    for (int x=0;x<7;++x)
      c3s[(y*7+x)*16 + oc] = fmaxf(acc[x] + b3s[oc], 0.f);
  }
  __syncthreads();

  // ---- phase 4: adaptive avg pool 7->4 (torch bins) ----
  {
    const int c = tid >> 4, p = (tid>>2)&3, q = tid&3;
    const int sp = (p==0)?0:(p==1)?1:(p==2)?3:5;
    const int ep = (p==0)?2:(p==1)?4:(p==2)?6:7;
    const int sq = (q==0)?0:(q==1)?1:(q==2)?3:5;
    const int eq = (q==0)?2:(q==1)?4:(q==2)?6:7;
    const float wp = (p==0||p==3) ? 0.5f : (1.f/3.f);
    const float wq = (q==0||q==3) ? 0.5f : (1.f/3.f);
    float sum = 0.f;
    for (int i=sp; i<ep; ++i)
      for (int j=sq; j<eq; ++j)
        sum += c3s[(i*7+j)*16 + c];
    feat[tid] = sum * wp * wq;   // tid == c*16 + p*4 + q  (flatten order)
  }
  __syncthreads();

  // ---- phase 5: fc (256->4) + tanh*pi ----
  {
    const int w = tid >> 6, lane = tid & 63;
    float partial = 0.f;
    #pragma unroll
    for (int j=0;j<4;++j){
      const int k = j*64 + lane;
      partial += feat[k] * fcwg[w*256 + k];
    }
    #pragma unroll
    for (int off=32; off>0; off>>=1) partial += __shfl_down(partial, off);
    if (lane==0)
      qin[(size_t)b*4 + w] = tanhf(partial + fcbg[w]) * 3.14159265358979323846f;
  }
}

// ---------------------------------------------------------------------------
// Kernel B: per-thread 4-qubit statevector sim + classifier head.
// wire w <-> bit mask (8 >> w)  [wire 0 most significant, matching reference]
// ---------------------------------------------------------------------------
template<int M>
__device__ __forceinline__ void g_ry(float* re, float* im, float c, float s){
  #pragma unroll
  for (int i=0;i<16;++i){
    if ((i & M)==0){
      const int j = i | M;
      const float r0=re[i], r1=re[j], q0=im[i], q1=im[j];
      re[i]=c*r0 - s*r1; re[j]=s*r0 + c*r1;
      im[i]=c*q0 - s*q1; im[j]=s*q0 + c*q1;
    }
  }
}
template<int M>
__device__ __forceinline__ void g_rz(float* re, float* im, float c, float s){
  #pragma unroll
  for (int i=0;i<16;++i){
    const float r=re[i], q=im[i];
    if ((i & M)==0){ re[i]=c*r + s*q; im[i]=c*q - s*r; }   // * e^{-i t/2}
    else           { re[i]=c*r - s*q; im[i]=c*q + s*r; }   // * e^{+i t/2}
  }
}
template<int CM,int TM>
__device__ __forceinline__ void g_cnot(float* re, float* im){
  #pragma unroll
  for (int i=0;i<16;++i){
    if ((i & CM) && !(i & TM)){
      const int j = i | TM;
      float t=re[i]; re[i]=re[j]; re[j]=t;
      t=im[i]; im[i]=im[j]; im[j]=t;
    }
  }
}

__global__ __launch_bounds__(256) void quantum_kernel(
    const float* __restrict__ qin, const float* __restrict__ qwg,
    const float* __restrict__ c1wg, const float* __restrict__ c1bg,
    const float* __restrict__ c2wg, const float* __restrict__ c2bg,
    float* __restrict__ out, int B)
{
  __shared__ float qc[32], qs[32], w1s[128], b1s[32], w2s[320], b2s[16];
  const int tid = threadIdx.x;
  if (tid < 32){ const float a = qwg[tid]*0.5f; qc[tid]=cosf(a); qs[tid]=sinf(a); }
  if (tid < 128) w1s[tid] = c1wg[tid];
  if (tid < 32)  b1s[tid] = c1bg[tid];
  for (int i=tid; i<320; i+=256) w2s[i] = c2wg[i];
  if (tid < 10)  b2s[tid] = c2bg[tid];
  __syncthreads();

  const int b = blockIdx.x*256 + tid;
  if (b >= B) return;

  const float4 ang = *(const float4*)(qin + (size_t)b*4);

  float re[16], im[16];
  #pragma unroll
  for (int i=0;i<16;++i){ re[i]=0.f; im[i]=0.f; }
  re[0] = 1.f;

  // angle encoding: RY(a_w) on wire w
  {
    float c,s;
    sincosf(ang.x*0.5f, &s, &c); g_ry<8>(re,im,c,s);
    sincosf(ang.y*0.5f, &s, &c); g_ry<4>(re,im,c,s);
    sincosf(ang.z*0.5f, &s, &c); g_ry<2>(re,im,c,s);
    sincosf(ang.w*0.5f, &s, &c); g_ry<1>(re,im,c,s);
  }

  // 4 variational layers: per wire RY,RZ then CNOT ring
  #pragma unroll
  for (int l=0; l<4; ++l){
    const int o = l*8;
    g_ry<8>(re,im,qc[o+0],qs[o+0]);  g_rz<8>(re,im,qc[o+1],qs[o+1]);
    g_ry<4>(re,im,qc[o+2],qs[o+2]);  g_rz<4>(re,im,qc[o+3],qs[o+3]);
    g_ry<2>(re,im,qc[o+4],qs[o+4]);  g_rz<2>(re,im,qc[o+5],qs[o+5]);
    g_ry<1>(re,im,qc[o+6],qs[o+6]);  g_rz<1>(re,im,qc[o+7],qs[o+7]);
    g_cnot<8,4>(re,im); g_cnot<4,2>(re,im); g_cnot<2,1>(re,im); g_cnot<1,8>(re,im);
  }

  // PauliZ expvals
  float p[16];
  #pragma unroll
  for (int i=0;i<16;++i) p[i] = re[i]*re[i] + im[i]*im[i];
  float z0=0.f, z1=0.f, z2=0.f, z3=0.f;
  #pragma unroll
  for (int i=0;i<16;++i){
    z0 += (i & 8) ? -p[i] : p[i];
    z1 += (i & 4) ? -p[i] : p[i];
    z2 += (i & 2) ? -p[i] : p[i];
    z3 += (i & 1) ? -p[i] : p[i];
  }

  // cls1 (4->32) + relu
  float h[32];
  #pragma unroll
  for (int o=0;o<32;++o){
    const float v = b1s[o] + z0*w1s[o*4+0] + z1*w1s[o*4+1]
                           + z2*w1s[o*4+2] + z3*w1s[o*4+3];
    h[o] = fmaxf(v, 0.f);
  }
  // cls2 (32->10)
  #pragma unroll
  for (int o=0;o<10;++o){
    float v = b2s[o];
    #pragma unroll
    for (int k=0;k<32;++k) v += h[k]*w2s[o*32+k];
    out[(size_t)b*10 + o] = v;
  }
}

// ---------------------------------------------------------------------------
extern "C" void kernel_launch(void* const* d_in, const int* in_sizes, int n_in,
                              void* d_out, int out_size, void* d_ws, size_t ws_size,
                              hipStream_t stream)
{
  const float* x   = (const float*)d_in[0];
  const float* w1  = (const float*)d_in[1];
  const float* b1  = (const float*)d_in[2];
  const float* w2  = (const float*)d_in[3];
  const float* b2  = (const float*)d_in[4];
  const float* w3  = (const float*)d_in[5];
  const float* b3  = (const float*)d_in[6];
  const float* fcw = (const float*)d_in[7];
  const float* fcb = (const float*)d_in[8];
  const float* qw  = (const float*)d_in[9];
  const float* c1w = (const float*)d_in[10];
  const float* c1b = (const float*)d_in[11];
  const float* c2w = (const float*)d_in[12];
  const float* c2b = (const float*)d_in[13];
  float* outp = (float*)d_out;

  const int B = in_sizes[0] / 784;
  float* qin = (float*)d_ws;                 // B*4 floats

  classical_kernel<<<B, TPB, 0, stream>>>(x, w1,b1, w2,b2, w3,b3, fcw,fcb, qin, B);

  const int nb = (B + 255) / 256;
  quantum_kernel<<<nb, 256, 0, stream>>>(qin, qw, c1w, c1b, c2w, c2b, outp, B);
}

// Round 2
// 334.821 us; speedup vs baseline: 2.4770x; 2.4770x over previous
//
#include <hip/hip_runtime.h>
#include <math.h>

#define TPB 256

typedef _Float16 f16;
typedef _Float16 f16x8 __attribute__((ext_vector_type(8)));
typedef float f32x4 __attribute__((ext_vector_type(4)));

__device__ __forceinline__ float dot4(float4 a, float4 b){
  return a.x*b.x + a.y*b.y + a.z*b.z + a.w*b.w;
}

// ---------------------------------------------------------------------------
// Kernel A: per-sample fused classical frontend, conv2/conv3 via f16 MFMA.
// One block (256 threads = 4 waves) per sample; all intermediates in LDS.
// conv2 implicit GEMM: M=196 (14x14), N=16 oc, K=72 -> pad 96, k = pos*8+ic
// conv3 implicit GEMM: M=49  (7x7),  N=16 oc, K=144 -> pad 160, k = pos*16+ic
// A and B fragments indexed with the SAME kappa(g,i)=g*8+i -> any HW k-perm
// cancels; C/D mapping col=lane&15, row=(lane>>4)*4+reg (HW-verified).
// ---------------------------------------------------------------------------
__global__ __launch_bounds__(TPB) void classical_kernel(
    const float* __restrict__ xg,
    const float* __restrict__ w1g, const float* __restrict__ b1g,
    const float* __restrict__ w2g, const float* __restrict__ b2g,
    const float* __restrict__ w3g, const float* __restrict__ b3g,
    const float* __restrict__ fcwg, const float* __restrict__ fcbg,
    float* __restrict__ qin, int B)
{
  __shared__ __align__(16) float xs[30*32];        // padded input, fp32
  __shared__ __align__(16) f16   c1s[16*16*8];     // conv1 out [r][c][ic], pad border 0
  __shared__ __align__(16) f16   w2s[16*96];       // [oc][pos(12)][ic(8)], pos>=9 zero
  __shared__ __align__(16) f16   w3s[16*160];      // [oc][k(160)], k=pos*16+ic, pos>=9 zero
  __shared__ __align__(16) f16   c2tmp[16*212];    // conv2 raw out [oc][m(<=207)]
  __shared__ __align__(16) f16   c2ps[9*9*16];     // pooled+relu [r][c][ic], pad border 0
  __shared__ __align__(16) f16   c3s[16*68];       // conv3 out [oc][m(<=63)]
  __shared__ __align__(16) float w1s[72];          // [oc][k]
  __shared__ float b1s[8], b2s[16], b3s[16];
  __shared__ __align__(16) float feat[256];

  const int tid = threadIdx.x;
  const int b   = blockIdx.x;
  const int lane = tid & 63, wv = tid >> 6;
  const int l15 = lane & 15, g = lane >> 4;

  // ---- phase 0: zero padded buffers + stage (reordered, f16) weights ----
  for (int i=tid; i<960; i+=TPB) xs[i] = 0.f;
  {
    unsigned* z1 = (unsigned*)c1s;                 // 2048 f16 = 1024 u32
    for (int i=tid; i<1024; i+=TPB) z1[i] = 0u;
    unsigned* z2 = (unsigned*)c2ps;                // 1296 f16 = 648 u32
    for (int i=tid; i<648; i+=TPB) z2[i] = 0u;
  }
  if (tid < 72) w1s[tid] = w1g[tid];
  if (tid < 8)  b1s[tid] = b1g[tid];
  if (tid < 16) b2s[tid] = b2g[tid];
  if (tid < 16) b3s[tid] = b3g[tid];
  // conv2_w (16,8,3,3): dst [oc][pos][ic] f16, pos 9..11 zero
  for (int i=tid; i<1536; i+=TPB){
    int oc = i/96, r = i%96, p = r>>3, ic = r&7;
    w2s[i] = (f16)(p < 9 ? w2g[oc*72 + ic*9 + p] : 0.f);
  }
  // conv3_w (16,16,3,3): dst [oc][k] f16, k=pos*16+ic, pos>=9 zero
  for (int i=tid; i<2560; i+=TPB){
    int oc = i/160, k = i%160, pos = k>>4, ic = k&15;
    w3s[i] = (f16)(pos < 9 ? w3g[oc*144 + ic*9 + pos] : 0.f);
  }
  __syncthreads();

  // ---- phase 0b: fill padded input interior ----
  for (int i=tid; i<784; i+=TPB){
    int y = i/28, x = i%28;
    xs[(y+1)*32 + (x+1)] = xg[(size_t)b*784 + i];
  }
  __syncthreads();

  // ---- phase 1: conv1 (1->8, stride2, pad1) + relu, fp32 VALU ----
  if (tid < 112){
    const int oc = tid / 14;
    const int oy = tid % 14;
    float acc[14];
    #pragma unroll
    for (int x=0;x<14;++x) acc[x] = b1s[oc];
    #pragma unroll
    for (int ky=0; ky<3; ++ky){
      float rv[32];
      #pragma unroll
      for (int c4=0;c4<8;++c4){
        float4 v = *(const float4*)&xs[(2*oy+ky)*32 + c4*4];
        rv[c4*4+0]=v.x; rv[c4*4+1]=v.y; rv[c4*4+2]=v.z; rv[c4*4+3]=v.w;
      }
      #pragma unroll
      for (int kx=0;kx<3;++kx){
        const float w = w1s[oc*9 + ky*3 + kx];
        #pragma unroll
        for (int x=0;x<14;++x) acc[x] += rv[2*x+kx] * w;
      }
    }
    #pragma unroll
    for (int x=0;x<14;++x)
      c1s[((oy+1)*16 + (x+1))*8 + oc] = (f16)fmaxf(acc[x], 0.f);
  }
  __syncthreads();

  // ---- phase 2: conv2 via MFMA (raw output, no bias/relu yet) ----
  {
    // B fragments: lane element i <-> k = kk*32 + g*8 + i = (kk*4+g)*8 + i
    f16x8 bf0 = *(const f16x8*)&w2s[l15*96 + (0*4 + g)*8];
    f16x8 bf1 = *(const f16x8*)&w2s[l15*96 + (1*4 + g)*8];
    f16x8 bf2 = *(const f16x8*)&w2s[l15*96 + (2*4 + g)*8];
    for (int tile = wv; tile < 13; tile += 4){
      unsigned m = (unsigned)(tile*16 + l15); if (m > 195u) m = 195u;
      const int rcb = (int)(m/14u)*16 + (int)(m%14u);   // padded base row*16+col
      f32x4 acc = {0.f,0.f,0.f,0.f};
      {
        int p = g;                                      // kk=0
        f16x8 a = *(const f16x8*)&c1s[(rcb + (p/3)*16 + (p%3))*8];
        acc = __builtin_amdgcn_mfma_f32_16x16x32_f16(a, bf0, acc, 0,0,0);
      }
      {
        int p = 4 + g;                                  // kk=1
        f16x8 a = *(const f16x8*)&c1s[(rcb + (p/3)*16 + (p%3))*8];
        acc = __builtin_amdgcn_mfma_f32_16x16x32_f16(a, bf1, acc, 0,0,0);
      }
      {
        int p = 8 + g; if (p > 8) p = 8;                // kk=2 (B rows >=9 are zero)
        f16x8 a = *(const f16x8*)&c1s[(rcb + (p/3)*16 + (p%3))*8];
        acc = __builtin_amdgcn_mfma_f32_16x16x32_f16(a, bf2, acc, 0,0,0);
      }
      // D[row=(g*4+j)][col=oc=l15] -> c2tmp[oc][tile*16+g*4+j], 4xf16 packed b64
      union { f16 h[4]; unsigned long long u; } pk;
      #pragma unroll
      for (int j=0;j<4;++j) pk.h[j] = (f16)acc[j];
      *(unsigned long long*)&c2tmp[l15*212 + tile*16 + g*4] = pk.u;
    }
  }
  __syncthreads();

  // ---- phase 3: maxpool2 + bias + relu -> c2ps [r][c][ic] ----
  for (int t=tid; t<784; t+=TPB){
    const int oc = t & 15, s = t >> 4;
    const int py = s / 7, px = s % 7;
    const int base = oc*212 + py*28 + px*2;
    const float v00 = (float)c2tmp[base],    v01 = (float)c2tmp[base+1];
    const float v10 = (float)c2tmp[base+14], v11 = (float)c2tmp[base+15];
    const float mx = fmaxf(fmaxf(v00,v01), fmaxf(v10,v11)) + b2s[oc];
    c2ps[((py+1)*9 + (px+1))*16 + oc] = (f16)fmaxf(mx, 0.f);
  }
  __syncthreads();

  // ---- phase 4: conv3 via MFMA + bias + relu ----
  {
    f16x8 cf[5];
    #pragma unroll
    for (int kk=0; kk<5; ++kk)
      cf[kk] = *(const f16x8*)&w3s[l15*160 + kk*32 + g*8];
    const int tile = wv;                                 // 4 tiles, 4 waves
    unsigned m = (unsigned)(tile*16 + l15); if (m > 48u) m = 48u;
    const int rcb = (int)(m/7u)*9 + (int)(m%7u);
    const int icb = (g & 1)*8;
    f32x4 acc = {0.f,0.f,0.f,0.f};
    #pragma unroll
    for (int kk=0; kk<5; ++kk){
      int p = 2*kk + (g>>1); if (p > 8) p = 8;           // B rows >=9 are zero
      f16x8 a = *(const f16x8*)&c2ps[(rcb + (p/3)*9 + (p%3))*16 + icb];
      acc = __builtin_amdgcn_mfma_f32_16x16x32_f16(a, cf[kk], acc, 0,0,0);
    }
    const float bias = b3s[l15];
    union { f16 h[4]; unsigned long long u; } pk;
    #pragma unroll
    for (int j=0;j<4;++j) pk.h[j] = (f16)fmaxf(acc[j] + bias, 0.f);
    *(unsigned long long*)&c3s[l15*68 + tile*16 + g*4] = pk.u;
  }
  __syncthreads();

  // ---- phase 5: adaptive avg pool 7->4 (torch bins) ----
  {
    const int c = tid >> 4, p = (tid>>2)&3, q = tid&3;
    const int sp = (p==0)?0:(p==1)?1:(p==2)?3:5;
    const int ep = (p==0)?2:(p==1)?4:(p==2)?6:7;
    const int sq = (q==0)?0:(q==1)?1:(q==2)?3:5;
    const int eq = (q==0)?2:(q==1)?4:(q==2)?6:7;
    const float wp = (p==0||p==3) ? 0.5f : (1.f/3.f);
    const float wq = (q==0||q==3) ? 0.5f : (1.f/3.f);
    float sum = 0.f;
    for (int i=sp; i<ep; ++i)
      for (int j=sq; j<eq; ++j)
        sum += (float)c3s[c*68 + i*7 + j];
    feat[tid] = sum * wp * wq;   // tid == c*16 + p*4 + q (flatten order)
  }
  __syncthreads();

  // ---- phase 6: fc (256->4) + tanh*pi ----
  {
    const int w = tid >> 6, ln = tid & 63;
    float partial = 0.f;
    #pragma unroll
    for (int j=0;j<4;++j){
      const int k = j*64 + ln;
      partial += feat[k] * fcwg[w*256 + k];
    }
    #pragma unroll
    for (int off=32; off>0; off>>=1) partial += __shfl_down(partial, off);
    if (ln==0)
      qin[(size_t)b*4 + w] = tanhf(partial + fcbg[w]) * 3.14159265358979323846f;
  }
}

// ---------------------------------------------------------------------------
// Kernel B: per-thread 4-qubit statevector sim + classifier head.
// wire w <-> bit mask (8 >> w)
// ---------------------------------------------------------------------------
template<int M>
__device__ __forceinline__ void g_ry(float* re, float* im, float c, float s){
  #pragma unroll
  for (int i=0;i<16;++i){
    if ((i & M)==0){
      const int j = i | M;
      const float r0=re[i], r1=re[j], q0=im[i], q1=im[j];
      re[i]=c*r0 - s*r1; re[j]=s*r0 + c*r1;
      im[i]=c*q0 - s*q1; im[j]=s*q0 + c*q1;
    }
  }
}
template<int M>
__device__ __forceinline__ void g_rz(float* re, float* im, float c, float s){
  #pragma unroll
  for (int i=0;i<16;++i){
    const float r=re[i], q=im[i];
    if ((i & M)==0){ re[i]=c*r + s*q; im[i]=c*q - s*r; }
    else           { re[i]=c*r - s*q; im[i]=c*q + s*r; }
  }
}
template<int CM,int TM>
__device__ __forceinline__ void g_cnot(float* re, float* im){
  #pragma unroll
  for (int i=0;i<16;++i){
    if ((i & CM) && !(i & TM)){
      const int j = i | TM;
      float t=re[i]; re[i]=re[j]; re[j]=t;
      t=im[i]; im[i]=im[j]; im[j]=t;
    }
  }
}

__global__ __launch_bounds__(256) void quantum_kernel(
    const float* __restrict__ qin, const float* __restrict__ qwg,
    const float* __restrict__ c1wg, const float* __restrict__ c1bg,
    const float* __restrict__ c2wg, const float* __restrict__ c2bg,
    float* __restrict__ out, int B)
{
  __shared__ float qc[32], qs[32], w1s[128], b1s[32], w2s[320], b2s[16];
  const int tid = threadIdx.x;
  if (tid < 32){ const float a = qwg[tid]*0.5f; qc[tid]=cosf(a); qs[tid]=sinf(a); }
  if (tid < 128) w1s[tid] = c1wg[tid];
  if (tid < 32)  b1s[tid] = c1bg[tid];
  for (int i=tid; i<320; i+=256) w2s[i] = c2wg[i];
  if (tid < 10)  b2s[tid] = c2bg[tid];
  __syncthreads();

  const int b = blockIdx.x*256 + tid;
  if (b >= B) return;

  const float4 ang = *(const float4*)(qin + (size_t)b*4);

  float re[16], im[16];
  #pragma unroll
  for (int i=0;i<16;++i){ re[i]=0.f; im[i]=0.f; }
  re[0] = 1.f;

  {
    float c,s;
    sincosf(ang.x*0.5f, &s, &c); g_ry<8>(re,im,c,s);
    sincosf(ang.y*0.5f, &s, &c); g_ry<4>(re,im,c,s);
    sincosf(ang.z*0.5f, &s, &c); g_ry<2>(re,im,c,s);
    sincosf(ang.w*0.5f, &s, &c); g_ry<1>(re,im,c,s);
  }

  #pragma unroll
  for (int l=0; l<4; ++l){
    const int o = l*8;
    g_ry<8>(re,im,qc[o+0],qs[o+0]);  g_rz<8>(re,im,qc[o+1],qs[o+1]);
    g_ry<4>(re,im,qc[o+2],qs[o+2]);  g_rz<4>(re,im,qc[o+3],qs[o+3]);
    g_ry<2>(re,im,qc[o+4],qs[o+4]);  g_rz<2>(re,im,qc[o+5],qs[o+5]);
    g_ry<1>(re,im,qc[o+6],qs[o+6]);  g_rz<1>(re,im,qc[o+7],qs[o+7]);
    g_cnot<8,4>(re,im); g_cnot<4,2>(re,im); g_cnot<2,1>(re,im); g_cnot<1,8>(re,im);
  }

  float p[16];
  #pragma unroll
  for (int i=0;i<16;++i) p[i] = re[i]*re[i] + im[i]*im[i];
  float z0=0.f, z1=0.f, z2=0.f, z3=0.f;
  #pragma unroll
  for (int i=0;i<16;++i){
    z0 += (i & 8) ? -p[i] : p[i];
    z1 += (i & 4) ? -p[i] : p[i];
    z2 += (i & 2) ? -p[i] : p[i];
    z3 += (i & 1) ? -p[i] : p[i];
  }

  float h[32];
  #pragma unroll
  for (int o=0;o<32;++o){
    const float v = b1s[o] + z0*w1s[o*4+0] + z1*w1s[o*4+1]
                           + z2*w1s[o*4+2] + z3*w1s[o*4+3];
    h[o] = fmaxf(v, 0.f);
  }
  #pragma unroll
  for (int o=0;o<10;++o){
    float v = b2s[o];
    #pragma unroll
    for (int k=0;k<32;++k) v += h[k]*w2s[o*32+k];
    out[(size_t)b*10 + o] = v;
  }
}

// ---------------------------------------------------------------------------
extern "C" void kernel_launch(void* const* d_in, const int* in_sizes, int n_in,
                              void* d_out, int out_size, void* d_ws, size_t ws_size,
                              hipStream_t stream)
{
  const float* x   = (const float*)d_in[0];
  const float* w1  = (const float*)d_in[1];
  const float* b1  = (const float*)d_in[2];
  const float* w2  = (const float*)d_in[3];
  const float* b2  = (const float*)d_in[4];
  const float* w3  = (const float*)d_in[5];
  const float* b3  = (const float*)d_in[6];
  const float* fcw = (const float*)d_in[7];
  const float* fcb = (const float*)d_in[8];
  const float* qw  = (const float*)d_in[9];
  const float* c1w = (const float*)d_in[10];
  const float* c1b = (const float*)d_in[11];
  const float* c2w = (const float*)d_in[12];
  const float* c2b = (const float*)d_in[13];
  float* outp = (float*)d_out;

  const int B = in_sizes[0] / 784;
  float* qin = (float*)d_ws;                 // B*4 floats

  classical_kernel<<<B, TPB, 0, stream>>>(x, w1,b1, w2,b2, w3,b3, fcw,fcb, qin, B);

  const int nb = (B + 255) / 256;
  quantum_kernel<<<nb, 256, 0, stream>>>(qin, qw, c1w, c1b, c2w, c2b, outp, B);
}

// Round 3
// 147.244 us; speedup vs baseline: 5.6324x; 2.2739x over previous
//
#include <hip/hip_runtime.h>
#include <math.h>

typedef _Float16 f16;
typedef _Float16 f16x8 __attribute__((ext_vector_type(8)));
typedef float f32x4 __attribute__((ext_vector_type(4)));

// workspace layout (bytes): [0,9216) staged f16 weights; [16384, +B*16) qin
#define WS_QIN_OFF 16384
// staged weight offsets (f16 elements)
#define OW1 0        // w1p [16][32]
#define OW2 512      // w2p [16][96]
#define OW3 2048     // w3p [16][160]

// wave-internal LDS fence: drains this wave's LDS/VMEM ops so cross-lane
// reads after writes are safe WITHOUT a block barrier (single-wave phases).
__device__ __forceinline__ void wfence(){
  __builtin_amdgcn_sched_barrier(0);
  asm volatile("s_waitcnt vmcnt(0) lgkmcnt(0)" ::: "memory");
  __builtin_amdgcn_sched_barrier(0);
}

// ---------------------------------------------------------------------------
// Precompute: reorder + f16-convert conv weights once (1 block).
// w1p[oc16][k32]: k=ky*3+kx (<9), oc<8, else 0
// w2p[oc16][p12][ic8]: p<9 else 0
// w3p[oc16][k160]: k=p*16+ic, p<9 else 0
// ---------------------------------------------------------------------------
__global__ void precompute_weights(const float* __restrict__ w1g,
                                   const float* __restrict__ w2g,
                                   const float* __restrict__ w3g,
                                   f16* __restrict__ wsw){
  const int tid = threadIdx.x;
  for (int i=tid; i<512; i+=256){
    int oc = i >> 5, k = i & 31;
    wsw[OW1 + i] = (f16)((oc < 8 && k < 9) ? w1g[oc*9 + k] : 0.f);
  }
  for (int i=tid; i<1536; i+=256){
    int oc = i/96, r = i%96, p = r>>3, ic = r&7;
    wsw[OW2 + i] = (f16)(p < 9 ? w2g[oc*72 + ic*9 + p] : 0.f);
  }
  for (int i=tid; i<2560; i+=256){
    int oc = i/160, k = i%160, pos = k>>4, ic = k&15;
    wsw[OW3 + i] = (f16)(pos < 9 ? w3g[oc*144 + ic*9 + pos] : 0.f);
  }
}

// ---------------------------------------------------------------------------
// Kernel A: one WAVE per sample, 4 waves/block, no block barriers after
// weight staging. All convs via mfma_f32_16x16x32_f16 with kappa(g,i)=g*8+i
// applied to both A and B operands (k-permutation cancels; R2-verified).
// C/D mapping: col=lane&15, row=(lane>>4)*4+reg.
// ---------------------------------------------------------------------------
__global__ __launch_bounds__(256) void classical_kernel(
    const float* __restrict__ xg,
    const float* __restrict__ b1g, const float* __restrict__ b2g,
    const float* __restrict__ b3g,
    const float* __restrict__ fcwg, const float* __restrict__ fcbg,
    const f16* __restrict__ wsw, float* __restrict__ qin, int B)
{
  __shared__ __align__(16) f16 wsh[4608];              // 9216B shared weights
  __shared__ __align__(16) unsigned char pw[4][10560]; // per-wave scratch

  const int tid = threadIdx.x, lane = tid & 63, wv = tid >> 6;
  const int l15 = lane & 15, g = lane >> 4;

  // block-wide: copy staged weights (9216B = 576 float4)
  {
    const float4* src = (const float4*)wsw;
    float4* dst = (float4*)wsh;
    for (int i=tid; i<576; i+=256) dst[i] = src[i];
  }
  __syncthreads();   // the only block barrier

  const int b = blockIdx.x*4 + wv;
  if (b >= B) return;

  // per-wave regions
  f16*   c1s  = (f16*)&pw[wv][0];      // [16 rows][18 cols][8 ic] = 4608B
  f16*   xs   = (f16*)&pw[wv][4608];   // [30 rows][34 cols] f16 = 2040B
  f16*   c2ps = xs;                    // overlay: [81 pos][24 ch] = 3888B
  f16*   c3n  = (f16*)&pw[wv][8496];   // [64 m][16 oc] = 2048B
  float* feat = (float*)c1s;           // overlay after conv2: 256 f32

  // ---- zero xs + c1s ----
  { unsigned* p = (unsigned*)xs;  for (int i=lane; i< 510; i+=64) p[i] = 0u; }
  { unsigned* p = (unsigned*)c1s; for (int i=lane; i<1152; i+=64) p[i] = 0u; }
  wfence();

  // ---- stage input (padded f16 [row+1][col+1], stride 34) ----
  for (int r=0; r<13; ++r){
    int i = r*64 + lane;
    if (i < 784){
      int y = i/28, x = i - y*28;
      xs[(y+1)*34 + (x+1)] = (f16)xg[(size_t)b*784 + i];
    }
  }
  wfence();

  // ---- conv1 (1->8, stride2, pad1) + relu via MFMA ----
  // tile = oy (14); lane: A row = x = l15, taps k=g*8+i -> t=ky*3+kx (<9)
  {
    f16x8 bw = *(const f16x8*)&wsh[OW1 + l15*32 + g*8];
    const float bias1 = b1g[l15 & 7];
    const unsigned* xsw = (const unsigned*)xs;     // u32 rows of 17
    for (int oy=0; oy<14; ++oy){
      const int r0 = (2*oy+0)*17 + l15;
      const int r1 = (2*oy+1)*17 + l15;
      const int r2 = (2*oy+2)*17 + l15;
      unsigned r0a = xsw[r0], r0b = xsw[r0+1];
      unsigned r1a = xsw[r1], r1b = xsw[r1+1];
      unsigned r2a = xsw[r2], r2b = xsw[r2+1];
      unsigned u0, u1, u2, u3;
      if (g == 0){
        u0 = r0a;
        u1 = (r0b & 0xffffu) | (r1a << 16);
        u2 = (r1a >> 16)     | (r1b << 16);
        u3 = r2a;
      } else if (g == 1){
        u0 = r2b & 0xffffu; u1 = 0u; u2 = 0u; u3 = 0u;
      } else { u0 = 0u; u1 = 0u; u2 = 0u; u3 = 0u; }
      union { unsigned u[4]; f16x8 v; } af;
      af.u[0]=u0; af.u[1]=u1; af.u[2]=u2; af.u[3]=u3;
      f32x4 acc = {0.f,0.f,0.f,0.f};
      acc = __builtin_amdgcn_mfma_f32_16x16x32_f16(af.v, bw, acc, 0,0,0);
      if (l15 < 8){
        #pragma unroll
        for (int j=0; j<4; ++j){
          int x = g*4 + j;
          if (x < 14)
            c1s[((oy+1)*18 + (x+1))*8 + l15] = (f16)fmaxf(acc[j] + bias1, 0.f);
        }
      }
    }
  }
  wfence();

  // ---- zero c2ps (overlays dead xs) ----
  { unsigned* p = (unsigned*)c2ps; for (int i=lane; i<972; i+=64) p[i] = 0u; }
  wfence();

  // ---- conv2 (8->16, pad1) + maxpool2 + bias + relu via MFMA ----
  // tile = row y (14); D row = x = g*4+j, D col = oc = l15.
  // Pool folds in-register across (even,odd) row-tile pairs.
  {
    f16x8 bf0 = *(const f16x8*)&wsh[OW2 + l15*96      + g*8];
    f16x8 bf1 = *(const f16x8*)&wsh[OW2 + l15*96 + 32 + g*8];
    f16x8 bf2 = *(const f16x8*)&wsh[OW2 + l15*96 + 64 + g*8];
    const float bias2 = b2g[l15];
    const int p0 = g,      r0o = p0/3, c0o = p0%3;   // kk=0: p=g
    const int p1 = 4 + g,  r1o = p1/3, c1o = p1%3;   // kk=1: p=4+g
    // kk=2: p=8+g, clamp->8 (B rows 9..11 are zero)
    float hA = 0.f, hB = 0.f;
    for (int y=0; y<14; ++y){
      f16x8 a0 = *(const f16x8*)&c1s[((y + r0o)*18 + l15 + c0o)*8];
      f16x8 a1 = *(const f16x8*)&c1s[((y + r1o)*18 + l15 + c1o)*8];
      f16x8 a2 = *(const f16x8*)&c1s[((y + 2  )*18 + l15 + 2  )*8];
      f32x4 acc = {0.f,0.f,0.f,0.f};
      acc = __builtin_amdgcn_mfma_f32_16x16x32_f16(a0, bf0, acc, 0,0,0);
      acc = __builtin_amdgcn_mfma_f32_16x16x32_f16(a1, bf1, acc, 0,0,0);
      acc = __builtin_amdgcn_mfma_f32_16x16x32_f16(a2, bf2, acc, 0,0,0);
      const float m0 = fmaxf(acc[0], acc[1]);   // x = 4g,4g+1   -> px=2g
      const float m1 = fmaxf(acc[2], acc[3]);   // x = 4g+2,4g+3 -> px=2g+1
      if ((y & 1) == 0){ hA = m0; hB = m1; }
      else {
        const int py = y >> 1;
        const float vA = fmaxf(fmaxf(hA, m0) + bias2, 0.f);
        const float vB = fmaxf(fmaxf(hB, m1) + bias2, 0.f);
        c2ps[((py+1)*9 + (2*g+1))*24 + l15] = (f16)vA;            // px=2g
        if (g < 3)
          c2ps[((py+1)*9 + (2*g+2))*24 + l15] = (f16)vB;          // px=2g+1
      }
    }
  }
  wfence();

  // ---- conv3 (16->16, pad1) + bias + relu via MFMA ----
  // 4 tiles; A pos m = tile*16+l15 (clamp 48); out [m][oc]
  {
    const float bias3 = b3g[l15];
    f16x8 cf0 = *(const f16x8*)&wsh[OW3 + l15*160       + g*8];
    f16x8 cf1 = *(const f16x8*)&wsh[OW3 + l15*160 +  32 + g*8];
    f16x8 cf2 = *(const f16x8*)&wsh[OW3 + l15*160 +  64 + g*8];
    f16x8 cf3 = *(const f16x8*)&wsh[OW3 + l15*160 +  96 + g*8];
    f16x8 cf4 = *(const f16x8*)&wsh[OW3 + l15*160 + 128 + g*8];
    const int gh = g >> 1, icb = (g & 1)*8;
    for (int tile=0; tile<4; ++tile){
      unsigned m = (unsigned)(tile*16 + l15); if (m > 48u) m = 48u;
      const int rcb = (int)(m/7u)*9 + (int)(m%7u);
      f32x4 acc = {0.f,0.f,0.f,0.f};
      #pragma unroll
      for (int kk=0; kk<5; ++kk){
        int p = 2*kk + gh; if (p > 8) p = 8;     // B rows pos>=9 are zero
        f16x8 a = *(const f16x8*)&c2ps[(rcb + (p/3)*9 + (p%3))*24 + icb];
        f16x8 bb = (kk==0)?cf0:(kk==1)?cf1:(kk==2)?cf2:(kk==3)?cf3:cf4;
        acc = __builtin_amdgcn_mfma_f32_16x16x32_f16(a, bb, acc, 0,0,0);
      }
      #pragma unroll
      for (int j=0; j<4; ++j)
        c3n[(tile*16 + g*4 + j)*16 + l15] = (f16)fmaxf(acc[j] + bias3, 0.f);
    }
  }
  wfence();

  // ---- adaptive avg pool 7->4 (torch bins) -> feat[256] f32 ----
  for (int r=0; r<4; ++r){
    const int t = r*64 + lane;
    const int c = t >> 4, pp = (t >> 2) & 3, q = t & 3;
    const int sp = (pp ? 2*pp-1 : 0), ep = (2*pp+2 < 7 ? 2*pp+2 : 7);
    const int sq = (q  ? 2*q -1 : 0), eq = (2*q +2 < 7 ? 2*q +2 : 7);
    float sum = 0.f;
    for (int i=sp; i<ep; ++i)
      for (int j=sq; j<eq; ++j)
        sum += (float)c3n[(i*7+j)*16 + c];
    const float wp = (pp==0||pp==3) ? 0.5f : (1.f/3.f);
    const float wq = (q ==0||q ==3) ? 0.5f : (1.f/3.f);
    feat[t] = sum * wp * wq;
  }
  wfence();

  // ---- fc (256->4) + tanh*pi ----
  {
    float s0=0.f, s1=0.f, s2=0.f, s3=0.f;
    #pragma unroll
    for (int j=0; j<4; ++j){
      const int k = j*64 + lane;
      const float f = feat[k];
      s0 += f * fcwg[k];
      s1 += f * fcwg[256 + k];
      s2 += f * fcwg[512 + k];
      s3 += f * fcwg[768 + k];
    }
    #pragma unroll
    for (int off=32; off; off>>=1){
      s0 += __shfl_xor(s0, off); s1 += __shfl_xor(s1, off);
      s2 += __shfl_xor(s2, off); s3 += __shfl_xor(s3, off);
    }
    if (lane < 4){
      const float s = (lane==0)?s0:(lane==1)?s1:(lane==2)?s2:s3;
      qin[(size_t)b*4 + lane] = tanhf(s + fcbg[lane]) * 3.14159265358979323846f;
    }
  }
}

// ---------------------------------------------------------------------------
// Kernel B: per-thread 4-qubit statevector sim + classifier head.
// wire w <-> bit mask (8 >> w)
// ---------------------------------------------------------------------------
template<int M>
__device__ __forceinline__ void g_ry(float* re, float* im, float c, float s){
  #pragma unroll
  for (int i=0;i<16;++i){
    if ((i & M)==0){
      const int j = i | M;
      const float r0=re[i], r1=re[j], q0=im[i], q1=im[j];
      re[i]=c*r0 - s*r1; re[j]=s*r0 + c*r1;
      im[i]=c*q0 - s*q1; im[j]=s*q0 + c*q1;
    }
  }
}
template<int M>
__device__ __forceinline__ void g_rz(float* re, float* im, float c, float s){
  #pragma unroll
  for (int i=0;i<16;++i){
    const float r=re[i], q=im[i];
    if ((i & M)==0){ re[i]=c*r + s*q; im[i]=c*q - s*r; }
    else           { re[i]=c*r - s*q; im[i]=c*q + s*r; }
  }
}
template<int CM,int TM>
__device__ __forceinline__ void g_cnot(float* re, float* im){
  #pragma unroll
  for (int i=0;i<16;++i){
    if ((i & CM) && !(i & TM)){
      const int j = i | TM;
      float t=re[i]; re[i]=re[j]; re[j]=t;
      t=im[i]; im[i]=im[j]; im[j]=t;
    }
  }
}

__global__ __launch_bounds__(256) void quantum_kernel(
    const float* __restrict__ qin, const float* __restrict__ qwg,
    const float* __restrict__ c1wg, const float* __restrict__ c1bg,
    const float* __restrict__ c2wg, const float* __restrict__ c2bg,
    float* __restrict__ out, int B)
{
  __shared__ float qc[32], qs[32], w1s[128], b1s[32], w2s[320], b2s[16];
  const int tid = threadIdx.x;
  if (tid < 32){ const float a = qwg[tid]*0.5f; qc[tid]=cosf(a); qs[tid]=sinf(a); }
  if (tid < 128) w1s[tid] = c1wg[tid];
  if (tid < 32)  b1s[tid] = c1bg[tid];
  for (int i=tid; i<320; i+=256) w2s[i] = c2wg[i];
  if (tid < 10)  b2s[tid] = c2bg[tid];
  __syncthreads();

  const int b = blockIdx.x*256 + tid;
  if (b >= B) return;

  const float4 ang = *(const float4*)(qin + (size_t)b*4);

  float re[16], im[16];
  #pragma unroll
  for (int i=0;i<16;++i){ re[i]=0.f; im[i]=0.f; }
  re[0] = 1.f;

  {
    float c,s;
    sincosf(ang.x*0.5f, &s, &c); g_ry<8>(re,im,c,s);
    sincosf(ang.y*0.5f, &s, &c); g_ry<4>(re,im,c,s);
    sincosf(ang.z*0.5f, &s, &c); g_ry<2>(re,im,c,s);
    sincosf(ang.w*0.5f, &s, &c); g_ry<1>(re,im,c,s);
  }

  #pragma unroll
  for (int l=0; l<4; ++l){
    const int o = l*8;
    g_ry<8>(re,im,qc[o+0],qs[o+0]);  g_rz<8>(re,im,qc[o+1],qs[o+1]);
    g_ry<4>(re,im,qc[o+2],qs[o+2]);  g_rz<4>(re,im,qc[o+3],qs[o+3]);
    g_ry<2>(re,im,qc[o+4],qs[o+4]);  g_rz<2>(re,im,qc[o+5],qs[o+5]);
    g_ry<1>(re,im,qc[o+6],qs[o+6]);  g_rz<1>(re,im,qc[o+7],qs[o+7]);
    g_cnot<8,4>(re,im); g_cnot<4,2>(re,im); g_cnot<2,1>(re,im); g_cnot<1,8>(re,im);
  }

  float p[16];
  #pragma unroll
  for (int i=0;i<16;++i) p[i] = re[i]*re[i] + im[i]*im[i];
  float z0=0.f, z1=0.f, z2=0.f, z3=0.f;
  #pragma unroll
  for (int i=0;i<16;++i){
    z0 += (i & 8) ? -p[i] : p[i];
    z1 += (i & 4) ? -p[i] : p[i];
    z2 += (i & 2) ? -p[i] : p[i];
    z3 += (i & 1) ? -p[i] : p[i];
  }

  float h[32];
  #pragma unroll
  for (int o=0;o<32;++o){
    const float v = b1s[o] + z0*w1s[o*4+0] + z1*w1s[o*4+1]
                           + z2*w1s[o*4+2] + z3*w1s[o*4+3];
    h[o] = fmaxf(v, 0.f);
  }
  #pragma unroll
  for (int o=0;o<10;++o){
    float v = b2s[o];
    #pragma unroll
    for (int k=0;k<32;++k) v += h[k]*w2s[o*32+k];
    out[(size_t)b*10 + o] = v;
  }
}

// ---------------------------------------------------------------------------
extern "C" void kernel_launch(void* const* d_in, const int* in_sizes, int n_in,
                              void* d_out, int out_size, void* d_ws, size_t ws_size,
                              hipStream_t stream)
{
  const float* x   = (const float*)d_in[0];
  const float* w1  = (const float*)d_in[1];
  const float* b1  = (const float*)d_in[2];
  const float* w2  = (const float*)d_in[3];
  const float* b2  = (const float*)d_in[4];
  const float* w3  = (const float*)d_in[5];
  const float* b3  = (const float*)d_in[6];
  const float* fcw = (const float*)d_in[7];
  const float* fcb = (const float*)d_in[8];
  const float* qw  = (const float*)d_in[9];
  const float* c1w = (const float*)d_in[10];
  const float* c1b = (const float*)d_in[11];
  const float* c2w = (const float*)d_in[12];
  const float* c2b = (const float*)d_in[13];
  float* outp = (float*)d_out;

  const int B = in_sizes[0] / 784;
  f16*   wsw = (f16*)d_ws;
  float* qin = (float*)((char*)d_ws + WS_QIN_OFF);

  precompute_weights<<<1, 256, 0, stream>>>(w1, w2, w3, wsw);

  classical_kernel<<<(B+3)/4, 256, 0, stream>>>(x, b1, b2, b3, fcw, fcb,
                                                wsw, qin, B);

  quantum_kernel<<<(B+255)/256, 256, 0, stream>>>(qin, qw, c1w, c1b,
                                                  c2w, c2b, outp, B);
}

// Round 4
// 105.261 us; speedup vs baseline: 7.8789x; 1.3988x over previous
//
#include <hip/hip_runtime.h>
#include <math.h>

typedef _Float16 f16;
typedef _Float16 f16x8 __attribute__((ext_vector_type(8)));
typedef float f32x4 __attribute__((ext_vector_type(4)));

// workspace: [0,9216) staged f16 weights; [16384, +B*16) qin
#define WS_QIN_OFF 16384
#define OW1 0        // w1p [16][32]  k=g*8+i: g=ky(<3), i=1..3 -> kx=i-1, else 0
#define OW2 512      // w2p [16][96]  [oc][pos(12)][ic8], pos>=9 zero
#define OW3 2048     // w3p [16][160] [oc][k], k=pos*16+ic, pos>=9 zero

// wave-internal fence: drain this wave's LDS/VMEM so cross-lane RAW is safe
// without a block barrier (each wave owns its LDS region).
__device__ __forceinline__ void wfence(){
  __builtin_amdgcn_sched_barrier(0);
  asm volatile("s_waitcnt vmcnt(0) lgkmcnt(0)" ::: "memory");
  __builtin_amdgcn_sched_barrier(0);
}

// ---------------------------------------------------------------------------
__global__ void precompute_weights(const float* __restrict__ w1g,
                                   const float* __restrict__ w2g,
                                   const float* __restrict__ w3g,
                                   f16* __restrict__ wsw){
  const int tid = threadIdx.x;
  // w1p: tap i=0 is the kx=-1 "garbage" slot -> zero weight
  for (int i=tid; i<512; i+=256){
    int oc = i >> 5, k = i & 31, gk = k >> 3, ii = k & 7;
    float v = 0.f;
    if (oc < 8 && gk < 3 && ii >= 1 && ii <= 3) v = w1g[oc*9 + gk*3 + (ii-1)];
    wsw[OW1 + i] = (f16)v;
  }
  for (int i=tid; i<1536; i+=256){
    int oc = i/96, r = i%96, p = r>>3, ic = r&7;
    wsw[OW2 + i] = (f16)(p < 9 ? w2g[oc*72 + ic*9 + p] : 0.f);
  }
  for (int i=tid; i<2560; i+=256){
    int oc = i/160, k = i%160, pos = k>>4, ic = k&15;
    wsw[OW3 + i] = (f16)(pos < 9 ? w3g[oc*144 + ic*9 + pos] : 0.f);
  }
}

// ---------------------------------------------------------------------------
// One WAVE per sample, 4 waves/block, ZERO block barriers.
// All MFMA operands indexed with kappa(g,i)=g*8+i on both A and B (any HW
// k-permutation cancels; validated R2/R3). Operand lane layouts (validated):
// arg0 rows = lane&15, arg1 cols = lane&15, k-chunk = lane>>4.
// D: col = lane&15, row = (lane>>4)*4 + reg.
// ---------------------------------------------------------------------------
__global__ __launch_bounds__(256, 4) void classical_kernel(
    const float* __restrict__ xg,
    const float* __restrict__ b1g, const float* __restrict__ b2g,
    const float* __restrict__ b3g,
    const float* __restrict__ fcwg, const float* __restrict__ fcbg,
    const f16* __restrict__ wsw, float* __restrict__ qin, int B)
{
  // per-wave: region A [0,3888) = xs [30][36] f16 (2160B), later c2ps [81][24]
  //           region B [3888,8496) = c1s [16][18][8] f16, later c3n [64][16]
  __shared__ __align__(16) unsigned char pw[4][8512];

  const int tid = threadIdx.x, lane = tid & 63, wv = tid >> 6;
  const int l15 = lane & 15, g = lane >> 4;

  const int b = blockIdx.x*4 + wv;
  if (b >= B) return;

  f16* xs   = (f16*)&pw[wv][0];       // [30][36], col = x_img+4, row = y_img+1
  f16* c2ps = xs;                     // overlay: [81 pos][24 ch]
  f16* c1s  = (f16*)&pw[wv][3888];    // [16 row][18 col][8 ic]
  f16* c3n  = c1s;                    // overlay after conv2: [64 pix][16 oc]

  // ---- zero xs (135 x16B) + c1s (288 x16B) ----
  {
    const f32x4 z4 = {0.f,0.f,0.f,0.f};
    f32x4* p0 = (f32x4*)xs;
    for (int i=lane; i<135; i+=64) p0[i] = z4;
    f32x4* p1 = (f32x4*)c1s;
    for (int i=lane; i<288; i+=64) p1[i] = z4;
  }

  // ---- stage input: float4 global -> 4xf16 b64 LDS ----
  {
    const float4* xg4 = (const float4*)(xg + (size_t)b*784);
    #pragma unroll
    for (int r=0; r<4; ++r){
      const int idx = r*64 + lane;
      if (idx < 196){
        float4 v = xg4[idx];
        int y = idx/7, xq = idx - y*7;
        union { f16 h[4]; unsigned long long u; } pk;
        pk.h[0]=(f16)v.x; pk.h[1]=(f16)v.y; pk.h[2]=(f16)v.z; pk.h[3]=(f16)v.w;
        *(unsigned long long*)&xs[(y+1)*36 + xq*4 + 4] = pk.u;
      }
    }
  }
  wfence();

  // ---- conv1 (1->8, stride2, pad1) + relu : A=weights, B=image ----
  // lane (l15,g): B[k=g*8+i][n=l15]: i=0 -> kx=-1 (zero weight, garbage ok),
  // i=1..3 -> kx=i-1 from xs row 2oy+g, i>=4 zeroed in-reg.
  // D[oc=g*4+j][x=l15] -> b64 write of 4 contiguous ic.
  {
    const f16x8 aw = *(const f16x8*)&wsw[OW1 + l15*32 + g*8];
    const float4 bv = ((const float4*)b1g)[g & 1];   // oc g*4..g*4+3 (g<2)
    const unsigned* xsw = (const unsigned*)xs;       // u32 rows of 18
    for (int oy=0; oy<14; ++oy){
      const int bu = (2*oy + g)*18 + l15 + 1;        // f16 col 2*l15+2
      union { unsigned u[4]; f16x8 v; } bf;
      bf.u[0] = xsw[bu];
      bf.u[1] = xsw[bu+1];
      bf.u[2] = 0u; bf.u[3] = 0u;
      f32x4 acc = {0.f,0.f,0.f,0.f};
      acc = __builtin_amdgcn_mfma_f32_16x16x32_f16(aw, bf.v, acc, 0,0,0);
      if (g < 2 && l15 < 14){
        union { f16 h[4]; unsigned long long u; } pk;
        #pragma unroll
        for (int j=0;j<4;++j) pk.h[j] = (f16)fmaxf(acc[j] + bv[j], 0.f);
        *(unsigned long long*)&c1s[((oy+1)*18 + (l15+1))*8 + g*4] = pk.u;
      }
    }
  }
  wfence();

  // ---- conv2 (8->16, pad1) + maxpool2 + bias + relu : A=image, B=weights ----
  {
    const f16x8 bf0 = *(const f16x8*)&wsw[OW2 + l15*96      + g*8];
    const f16x8 bf1 = *(const f16x8*)&wsw[OW2 + l15*96 + 32 + g*8];
    const f16x8 bf2 = *(const f16x8*)&wsw[OW2 + l15*96 + 64 + g*8];
    const float bias2 = b2g[l15];
    // zero c2ps (overlays xs; conv1 reads are fenced above; these zero-writes
    // precede this wave's pool-writes in program order -> ordered in LDS)
    {
      const f32x4 z4 = {0.f,0.f,0.f,0.f};
      f32x4* p = (f32x4*)c2ps;
      for (int i=lane; i<243; i+=64) p[i] = z4;
    }
    const int p0 = g,     r0o = p0/3, c0o = p0%3;
    const int p1 = 4 + g, r1o = p1/3, c1o = p1%3;
    float hA = 0.f, hB = 0.f;
    for (int y=0; y<14; ++y){
      f16x8 a0 = *(const f16x8*)&c1s[((y + r0o)*18 + l15 + c0o)*8];
      f16x8 a1 = *(const f16x8*)&c1s[((y + r1o)*18 + l15 + c1o)*8];
      f16x8 a2 = *(const f16x8*)&c1s[((y + 2  )*18 + l15 + 2  )*8];
      f32x4 acc = {0.f,0.f,0.f,0.f};
      acc = __builtin_amdgcn_mfma_f32_16x16x32_f16(a0, bf0, acc, 0,0,0);
      acc = __builtin_amdgcn_mfma_f32_16x16x32_f16(a1, bf1, acc, 0,0,0);
      acc = __builtin_amdgcn_mfma_f32_16x16x32_f16(a2, bf2, acc, 0,0,0);
      const float m0 = fmaxf(acc[0], acc[1]);   // x = 4g,4g+1   -> px=2g
      const float m1 = fmaxf(acc[2], acc[3]);   // x = 4g+2,4g+3 -> px=2g+1
      if ((y & 1) == 0){ hA = m0; hB = m1; }
      else {
        const int py = y >> 1;
        const float vA = fmaxf(fmaxf(hA, m0) + bias2, 0.f);
        const float vB = fmaxf(fmaxf(hB, m1) + bias2, 0.f);
        c2ps[((py+1)*9 + (2*g+1))*24 + l15] = (f16)vA;        // px=2g
        if (g < 3)
          c2ps[((py+1)*9 + (2*g+2))*24 + l15] = (f16)vB;      // px=2g+1
      }
    }
  }
  wfence();

  // ---- conv3 (16->16, pad1) + bias + relu : A=weights, B=image ----
  // D[oc=g*4+j][pix-in-tile=l15] -> b64 write of 4 contiguous oc... transposed:
  // c3n[pix][oc]: lane writes oc g*4..g*4+3 at its pix -> b64.
  {
    f16x8 cf[5];
    #pragma unroll
    for (int kk=0; kk<5; ++kk)
      cf[kk] = *(const f16x8*)&wsw[OW3 + l15*160 + kk*32 + g*8];
    const float4 bv3 = ((const float4*)b3g)[g];   // oc g*4..g*4+3
    const int gh = g >> 1, icb = (g & 1)*8;
    #pragma unroll
    for (int tile=0; tile<4; ++tile){
      unsigned m = (unsigned)(tile*16 + l15); if (m > 48u) m = 48u;
      const int rcb = (int)(m/7u)*9 + (int)(m%7u);
      f32x4 acc = {0.f,0.f,0.f,0.f};
      #pragma unroll
      for (int kk=0; kk<5; ++kk){
        int p = 2*kk + gh; if (p > 8) p = 8;      // A rows pos>=9 are zero
        f16x8 a = *(const f16x8*)&c2ps[(rcb + (p/3)*9 + (p%3))*24 + icb];
        acc = __builtin_amdgcn_mfma_f32_16x16x32_f16(cf[kk], a, acc, 0,0,0);
      }
      union { f16 h[4]; unsigned long long u; } pk;
      #pragma unroll
      for (int j=0;j<4;++j) pk.h[j] = (f16)fmaxf(acc[j] + bv3[j], 0.f);
      *(unsigned long long*)&c3n[(tile*16 + l15)*16 + g*4] = pk.u;
    }
  }
  wfence();

  // ---- adaptive avg pool 7->4 (torch bins), fixed 3x3 window w/ zero wts ----
  float freg[4];
  {
    #pragma unroll
    for (int r=0; r<4; ++r){
      const int t = r*64 + lane;
      const int c = t >> 4, p2 = (t >> 2) & 3, q2 = t & 3;
      const int sp = p2 ? 2*p2 - 1 : 0;
      const int sq = q2 ? 2*q2 - 1 : 0;
      const float th = 1.f/3.f;
      const float wr2 = (p2==1 || p2==2) ? th : 0.f;
      const float wra = (p2==1 || p2==2) ? th : 0.5f;
      const float wc2 = (q2==1 || q2==2) ? th : 0.f;
      const float wca = (q2==1 || q2==2) ? th : 0.5f;
      float rs[3];
      #pragma unroll
      for (int di=0; di<3; ++di){
        const int rowb = (sp + di)*7 + sq;
        const float v0 = (float)c3n[(rowb    )*16 + c];
        const float v1 = (float)c3n[(rowb + 1)*16 + c];
        const float v2 = (float)c3n[(rowb + 2)*16 + c];
        rs[di] = wca*(v0 + v1) + wc2*v2;
      }
      freg[r] = wra*(rs[0] + rs[1]) + wr2*rs[2];
    }
  }

  // ---- fc (256->4) + tanh*pi (feat stays in registers; k = r*64+lane) ----
  {
    float s0=0.f, s1=0.f, s2=0.f, s3=0.f;
    #pragma unroll
    for (int j=0; j<4; ++j){
      const int k = j*64 + lane;
      const float f = freg[j];
      s0 += f * fcwg[k];
      s1 += f * fcwg[256 + k];
      s2 += f * fcwg[512 + k];
      s3 += f * fcwg[768 + k];
    }
    #pragma unroll
    for (int off=32; off; off>>=1){
      s0 += __shfl_xor(s0, off); s1 += __shfl_xor(s1, off);
      s2 += __shfl_xor(s2, off); s3 += __shfl_xor(s3, off);
    }
    if (lane < 4){
      const float s = (lane==0)?s0:(lane==1)?s1:(lane==2)?s2:s3;
      qin[(size_t)b*4 + lane] = tanhf(s + fcbg[lane]) * 3.14159265358979323846f;
    }
  }
}

// ---------------------------------------------------------------------------
// Kernel B: per-thread 4-qubit statevector sim + classifier head.
// wire w <-> bit mask (8 >> w)
// ---------------------------------------------------------------------------
template<int M>
__device__ __forceinline__ void g_ry(float* re, float* im, float c, float s){
  #pragma unroll
  for (int i=0;i<16;++i){
    if ((i & M)==0){
      const int j = i | M;
      const float r0=re[i], r1=re[j], q0=im[i], q1=im[j];
      re[i]=c*r0 - s*r1; re[j]=s*r0 + c*r1;
      im[i]=c*q0 - s*q1; im[j]=s*q0 + c*q1;
    }
  }
}
template<int M>
__device__ __forceinline__ void g_rz(float* re, float* im, float c, float s){
  #pragma unroll
  for (int i=0;i<16;++i){
    const float r=re[i], q=im[i];
    if ((i & M)==0){ re[i]=c*r + s*q; im[i]=c*q - s*r; }
    else           { re[i]=c*r - s*q; im[i]=c*q + s*r; }
  }
}
template<int CM,int TM>
__device__ __forceinline__ void g_cnot(float* re, float* im){
  #pragma unroll
  for (int i=0;i<16;++i){
    if ((i & CM) && !(i & TM)){
      const int j = i | TM;
      float t=re[i]; re[i]=re[j]; re[j]=t;
      t=im[i]; im[i]=im[j]; im[j]=t;
    }
  }
}

__global__ __launch_bounds__(256) void quantum_kernel(
    const float* __restrict__ qin, const float* __restrict__ qwg,
    const float* __restrict__ c1wg, const float* __restrict__ c1bg,
    const float* __restrict__ c2wg, const float* __restrict__ c2bg,
    float* __restrict__ out, int B)
{
  __shared__ float qc[32], qs[32], w1s[128], b1s[32], w2s[320], b2s[16];
  const int tid = threadIdx.x;
  if (tid < 32){ const float a = qwg[tid]*0.5f; qc[tid]=cosf(a); qs[tid]=sinf(a); }
  if (tid < 128) w1s[tid] = c1wg[tid];
  if (tid < 32)  b1s[tid] = c1bg[tid];
  for (int i=tid; i<320; i+=256) w2s[i] = c2wg[i];
  if (tid < 10)  b2s[tid] = c2bg[tid];
  __syncthreads();

  const int b = blockIdx.x*256 + tid;
  if (b >= B) return;

  const float4 ang = *(const float4*)(qin + (size_t)b*4);

  float re[16], im[16];
  #pragma unroll
  for (int i=0;i<16;++i){ re[i]=0.f; im[i]=0.f; }
  re[0] = 1.f;

  {
    float c,s;
    sincosf(ang.x*0.5f, &s, &c); g_ry<8>(re,im,c,s);
    sincosf(ang.y*0.5f, &s, &c); g_ry<4>(re,im,c,s);
    sincosf(ang.z*0.5f, &s, &c); g_ry<2>(re,im,c,s);
    sincosf(ang.w*0.5f, &s, &c); g_ry<1>(re,im,c,s);
  }

  #pragma unroll
  for (int l=0; l<4; ++l){
    const int o = l*8;
    g_ry<8>(re,im,qc[o+0],qs[o+0]);  g_rz<8>(re,im,qc[o+1],qs[o+1]);
    g_ry<4>(re,im,qc[o+2],qs[o+2]);  g_rz<4>(re,im,qc[o+3],qs[o+3]);
    g_ry<2>(re,im,qc[o+4],qs[o+4]);  g_rz<2>(re,im,qc[o+5],qs[o+5]);
    g_ry<1>(re,im,qc[o+6],qs[o+6]);  g_rz<1>(re,im,qc[o+7],qs[o+7]);
    g_cnot<8,4>(re,im); g_cnot<4,2>(re,im); g_cnot<2,1>(re,im); g_cnot<1,8>(re,im);
  }

  float p[16];
  #pragma unroll
  for (int i=0;i<16;++i) p[i] = re[i]*re[i] + im[i]*im[i];
  float z0=0.f, z1=0.f, z2=0.f, z3=0.f;
  #pragma unroll
  for (int i=0;i<16;++i){
    z0 += (i & 8) ? -p[i] : p[i];
    z1 += (i & 4) ? -p[i] : p[i];
    z2 += (i & 2) ? -p[i] : p[i];
    z3 += (i & 1) ? -p[i] : p[i];
  }

  float h[32];
  #pragma unroll
  for (int o=0;o<32;++o){
    const float v = b1s[o] + z0*w1s[o*4+0] + z1*w1s[o*4+1]
                           + z2*w1s[o*4+2] + z3*w1s[o*4+3];
    h[o] = fmaxf(v, 0.f);
  }
  #pragma unroll
  for (int o=0;o<10;++o){
    float v = b2s[o];
    #pragma unroll
    for (int k=0;k<32;++k) v += h[k]*w2s[o*32+k];
    out[(size_t)b*10 + o] = v;
  }
}

// ---------------------------------------------------------------------------
extern "C" void kernel_launch(void* const* d_in, const int* in_sizes, int n_in,
                              void* d_out, int out_size, void* d_ws, size_t ws_size,
                              hipStream_t stream)
{
  const float* x   = (const float*)d_in[0];
  const float* w1  = (const float*)d_in[1];
  const float* b1  = (const float*)d_in[2];
  const float* w2  = (const float*)d_in[3];
  const float* b2  = (const float*)d_in[4];
  const float* w3  = (const float*)d_in[5];
  const float* b3  = (const float*)d_in[6];
  const float* fcw = (const float*)d_in[7];
  const float* fcb = (const float*)d_in[8];
  const float* qw  = (const float*)d_in[9];
  const float* c1w = (const float*)d_in[10];
  const float* c1b = (const float*)d_in[11];
  const float* c2w = (const float*)d_in[12];
  const float* c2b = (const float*)d_in[13];
  float* outp = (float*)d_out;

  const int B = in_sizes[0] / 784;
  f16*   wsw = (f16*)d_ws;
  float* qin = (float*)((char*)d_ws + WS_QIN_OFF);

  precompute_weights<<<1, 256, 0, stream>>>(w1, w2, w3, wsw);

  classical_kernel<<<(B+3)/4, 256, 0, stream>>>(x, b1, b2, b3, fcw, fcb,
                                                wsw, qin, B);

  quantum_kernel<<<(B+255)/256, 256, 0, stream>>>(qin, qw, c1w, c1b,
                                                  c2w, c2b, outp, B);
}

// Round 6
// 86.595 us; speedup vs baseline: 9.5773x; 1.2156x over previous
//
#include <hip/hip_runtime.h>
#include <math.h>

typedef _Float16 f16;
typedef _Float16 f16x8 __attribute__((ext_vector_type(8)));
typedef float f32x4 __attribute__((ext_vector_type(4)));

// workspace: [0,16384) staged f16 weights; [16384, +B*16) qin
#define WS_QIN_OFF 16384
#define OW1   0      // [16][32] conv1 [oc][k] k=gk*8+ii: gk=ky, ii=1..3 -> kx=ii-1
#define OW2   512    // [16][96] conv2 [oc][pos12][ic8], pos>=9 zero
#define OW3   2048   // [16][160] conv3 [oc][k], k=pos*16+ic, pos>=9 zero
#define OPOOL 4608   // [16][64] 36x pool matrix (entries 9/6/4 exact f16)

// wave-internal fence: drain this wave's LDS/VMEM so cross-lane RAW is safe
// without a block barrier (each wave owns its LDS region).
__device__ __forceinline__ void wfence(){
  __builtin_amdgcn_sched_barrier(0);
  asm volatile("s_waitcnt vmcnt(0) lgkmcnt(0)" ::: "memory");
  __builtin_amdgcn_sched_barrier(0);
}

// ---------------------------------------------------------------------------
__global__ void precompute_weights(const float* __restrict__ w1g,
                                   const float* __restrict__ w2g,
                                   const float* __restrict__ w3g,
                                   f16* __restrict__ wsw){
  const int tid = threadIdx.x;
  // conv1 weights (R4-proven): rows oc<8, chunk gk=ky, ii=0 is the kx=-1
  // garbage slot (zero weight), ii=1..3 -> kx=ii-1, ii>=4 zero.
  for (int i=tid; i<512; i+=256){
    int oc = i >> 5, k = i & 31, gk = k >> 3, ii = k & 7;
    float v = 0.f;
    if (oc < 8 && gk < 3 && ii >= 1 && ii <= 3) v = w1g[oc*9 + gk*3 + (ii-1)];
    wsw[OW1 + i] = (f16)v;
  }
  for (int i=tid; i<1536; i+=256){
    int oc = i/96, r = i%96, p = r>>3, ic = r&7;
    wsw[OW2 + i] = (f16)(p < 9 ? w2g[oc*72 + ic*9 + p] : 0.f);
  }
  for (int i=tid; i<2560; i+=256){
    int oc = i/160, k = i%160, pos = k>>4, ic = k&15;
    wsw[OW3 + i] = (f16)(pos < 9 ? w3g[oc*144 + ic*9 + pos] : 0.f);
  }
  // 36x adaptive-pool matrix: P36[pq][pix], exact {9,6,4} in f16
  for (int i=tid; i<1024; i+=256){
    int pq = i >> 6, pix = i & 63;
    float v = 0.f;
    if (pix < 49){
      int p = pq >> 2, q = pq & 3, ii = pix/7, jj = pix%7;
      int sp = (p*7) >> 2, ep = (7*(p+1)+3) >> 2;
      int sq = (q*7) >> 2, eq = (7*(q+1)+3) >> 2;
      if (ii >= sp && ii < ep && jj >= sq && jj < eq)
        v = 36.f / (float)((ep-sp)*(eq-sq));
    }
    wsw[OPOOL + i] = (f16)v;
  }
}

// ---------------------------------------------------------------------------
// One WAVE per sample, 4 waves/block, zero block barriers. All MFMA operands
// indexed with kappa(g,i)=g*8+i on both operands (HW k-perm cancels;
// validated R2-R4). D-mapping (pinned by R2 conv2 + R4 conv3, opposite arg
// orders both end-to-end validated): D rows <- arg0's per-lane index,
// D cols <- arg1's; lane (l15,g) reg j holds D[g*4+j][l15].
// ---------------------------------------------------------------------------
__global__ __launch_bounds__(256, 4) void classical_kernel(
    const float* __restrict__ xg,
    const float* __restrict__ b1g, const float* __restrict__ b2g,
    const float* __restrict__ b3g,
    const float* __restrict__ fcwg, const float* __restrict__ fcbg,
    const f16* __restrict__ wsw, float* __restrict__ qin, int B)
{
  // per-wave: region A [0,3888)   = xs [30][36] f16, later c2ps [81][24]
  //           region B [3888,8752)= c1s [16][19][8] f16, later c3t [16][72]
  __shared__ __align__(16) unsigned char pw[4][8768];

  const int tid = threadIdx.x, lane = tid & 63, wv = tid >> 6;
  const int l15 = lane & 15, g = lane >> 4;

  const int b = blockIdx.x*4 + wv;
  if (b >= B) return;

  f16* xs   = (f16*)&pw[wv][0];       // [30][36], col = x_img+4, row = y_img+1
  f16* c2ps = xs;                     // overlay: [81 pos][24 ch]
  f16* c1s  = (f16*)&pw[wv][3888];    // [16 row][19 col][8 ic]  (pad19: banks)
  f16* c3t  = c1s;                    // overlay: [16 oc][72 pix] (144B rows)

  // ---- zero xs (135 x16B) + c1s (304 x16B) ----
  {
    const f32x4 z4 = {0.f,0.f,0.f,0.f};
    f32x4* p0 = (f32x4*)xs;
    for (int i=lane; i<135; i+=64) p0[i] = z4;
    f32x4* p1 = (f32x4*)c1s;
    for (int i=lane; i<304; i+=64) p1[i] = z4;
  }

  // ---- stage input: float4 global -> 4xf16 b64 LDS ----
  {
    const float4* xg4 = (const float4*)(xg + (size_t)b*784);
    #pragma unroll
    for (int r=0; r<4; ++r){
      const int idx = r*64 + lane;
      if (idx < 196){
        float4 v = xg4[idx];
        int y = idx/7, xq = idx - y*7;
        union { f16 h[4]; unsigned long long u; } pk;
        pk.h[0]=(f16)v.x; pk.h[1]=(f16)v.y; pk.h[2]=(f16)v.z; pk.h[3]=(f16)v.w;
        *(unsigned long long*)&xs[(y+1)*36 + xq*4 + 4] = pk.u;
      }
    }
  }
  wfence();

  // ---- conv1 (1->8, stride2, pad1) + relu via MFMA (R4-proven form) ----
  // A=weights (rows oc), B=image: chunk g = ky, taps i=0 -> kx=-1 (zero wt),
  // i=1..3 -> kx=i-1, i>=4 zeroed. D[oc=g*4+j][x=l15], write b64 (4 ic).
  {
    const f16x8 aw = *(const f16x8*)&wsw[OW1 + l15*32 + g*8];
    const float4 bv = ((const float4*)b1g)[g & 1];   // oc g*4..g*4+3 (g<2)
    const unsigned* xsw = (const unsigned*)xs;       // u32 rows of 18
    for (int oy=0; oy<14; ++oy){
      const int bu = (2*oy + g)*18 + l15 + 1;        // f16 col 2*l15+2
      union { unsigned u[4]; f16x8 v; } bf;
      bf.u[0] = xsw[bu];
      bf.u[1] = xsw[bu+1];
      bf.u[2] = 0u; bf.u[3] = 0u;
      f32x4 acc = {0.f,0.f,0.f,0.f};
      acc = __builtin_amdgcn_mfma_f32_16x16x32_f16(aw, bf.v, acc, 0,0,0);
      if (g < 2 && l15 < 14){
        union { f16 h[4]; unsigned long long u; } pk;
        #pragma unroll
        for (int j=0;j<4;++j) pk.h[j] = (f16)fmaxf(acc[j] + bv[j], 0.f);
        *(unsigned long long*)&c1s[((oy+1)*19 + (l15+1))*8 + g*4] = pk.u;
      }
    }
  }
  wfence();

  // ---- conv2 (8->16, pad1) + maxpool2 + bias + relu via MFMA ----
  // A=image (m=x), B=weights (n=oc); pool folds in-register.
  {
    const f16x8 bf0 = *(const f16x8*)&wsw[OW2 + l15*96      + g*8];
    const f16x8 bf1 = *(const f16x8*)&wsw[OW2 + l15*96 + 32 + g*8];
    const f16x8 bf2 = *(const f16x8*)&wsw[OW2 + l15*96 + 64 + g*8];
    const float bias2 = b2g[l15];
    // zero c2ps (overlays dead xs; conv1's xs reads drained by wfence above)
    {
      const f32x4 z4 = {0.f,0.f,0.f,0.f};
      f32x4* p = (f32x4*)c2ps;
      for (int i=lane; i<243; i+=64) p[i] = z4;
    }
    const int p0 = g,     r0o = p0/3, c0o = p0%3;
    const int p1 = 4 + g, r1o = p1/3, c1o = p1%3;
    float hA = 0.f, hB = 0.f;
    for (int y=0; y<14; ++y){
      f16x8 a0 = *(const f16x8*)&c1s[((y + r0o)*19 + l15 + c0o)*8];
      f16x8 a1 = *(const f16x8*)&c1s[((y + r1o)*19 + l15 + c1o)*8];
      f16x8 a2 = *(const f16x8*)&c1s[((y + 2  )*19 + l15 + 2  )*8];
      f32x4 acc = {0.f,0.f,0.f,0.f};
      acc = __builtin_amdgcn_mfma_f32_16x16x32_f16(a0, bf0, acc, 0,0,0);
      acc = __builtin_amdgcn_mfma_f32_16x16x32_f16(a1, bf1, acc, 0,0,0);
      acc = __builtin_amdgcn_mfma_f32_16x16x32_f16(a2, bf2, acc, 0,0,0);
      const float m0 = fmaxf(acc[0], acc[1]);   // x = 4g,4g+1   -> px=2g
      const float m1 = fmaxf(acc[2], acc[3]);   // x = 4g+2,4g+3 -> px=2g+1
      if ((y & 1) == 0){ hA = m0; hB = m1; }
      else {
        const int py = y >> 1;
        const float vA = fmaxf(fmaxf(hA, m0) + bias2, 0.f);
        const float vB = fmaxf(fmaxf(hB, m1) + bias2, 0.f);
        c2ps[((py+1)*9 + (2*g+1))*24 + l15] = (f16)vA;        // px=2g
        if (g < 3)
          c2ps[((py+1)*9 + (2*g+2))*24 + l15] = (f16)vB;      // px=2g+1
      }
    }
  }
  wfence();

  // ---- conv3 (16->16, pad1) + bias + relu : A=image, B=weights ----
  // D[m=pix-in-tile=g*4+j][n=oc=l15]; bias per oc=l15 (constant across j);
  // store c3t[oc=l15][pix=tile*16+g*4+j], b64. Tile3 pix 49..63 are clamped
  // duplicates of pix 48 (finite), zero pool weight.
  {
    f16x8 cf[5];
    #pragma unroll
    for (int kk=0; kk<5; ++kk)
      cf[kk] = *(const f16x8*)&wsw[OW3 + l15*160 + kk*32 + g*8];
    const float bias3 = b3g[l15];
    const int gh = g >> 1, icb = (g & 1)*8;
    #pragma unroll
    for (int tile=0; tile<4; ++tile){
      unsigned m = (unsigned)(tile*16 + l15); if (m > 48u) m = 48u;
      const int rcb = (int)(m/7u)*9 + (int)(m%7u);
      f32x4 acc = {0.f,0.f,0.f,0.f};
      #pragma unroll
      for (int kk=0; kk<5; ++kk){
        int p = 2*kk + gh; if (p > 8) p = 8;      // weight rows pos>=9 zero
        f16x8 a = *(const f16x8*)&c2ps[(rcb + (p/3)*9 + (p%3))*24 + icb];
        acc = __builtin_amdgcn_mfma_f32_16x16x32_f16(a, cf[kk], acc, 0,0,0);
      }
      union { f16 h[4]; unsigned long long u; } pk;
      #pragma unroll
      for (int j=0;j<4;++j) pk.h[j] = (f16)fmaxf(acc[j] + bias3, 0.f);
      *(unsigned long long*)&c3t[l15*72 + tile*16 + g*4] = pk.u;
    }
  }
  wfence();

  // ---- adaptive pool as 2 MFMAs: D[m=pq][n=oc] = 36*feat[oc][pq] ----
  // A=P36 (arg0, rows pq), B=c3t (arg1, cols oc). Lane reg j holds
  // 36*feat[oc=l15][pq=g*4+j] -> flatten t = l15*16 + g*4 + j.
  f32x4 pacc = {0.f,0.f,0.f,0.f};
  {
    const f16x8 pA0 = *(const f16x8*)&wsw[OPOOL + l15*64      + g*8];
    const f16x8 pA1 = *(const f16x8*)&wsw[OPOOL + l15*64 + 32 + g*8];
    const f16x8 pB0 = *(const f16x8*)&c3t[l15*72      + g*8];
    const f16x8 pB1 = *(const f16x8*)&c3t[l15*72 + 32 + g*8];
    pacc = __builtin_amdgcn_mfma_f32_16x16x32_f16(pA0, pB0, pacc, 0,0,0);
    pacc = __builtin_amdgcn_mfma_f32_16x16x32_f16(pA1, pB1, pacc, 0,0,0);
  }

  // ---- fc (256->4) + tanh*pi : shfl_xor butterfly (R3/R4-proven) ----
  {
    const float4 fw0 = *(const float4*)&fcwg[      l15*16 + g*4];
    const float4 fw1 = *(const float4*)&fcwg[256 + l15*16 + g*4];
    const float4 fw2 = *(const float4*)&fcwg[512 + l15*16 + g*4];
    const float4 fw3 = *(const float4*)&fcwg[768 + l15*16 + g*4];
    float s0 = pacc[0]*fw0.x + pacc[1]*fw0.y + pacc[2]*fw0.z + pacc[3]*fw0.w;
    float s1 = pacc[0]*fw1.x + pacc[1]*fw1.y + pacc[2]*fw1.z + pacc[3]*fw1.w;
    float s2 = pacc[0]*fw2.x + pacc[1]*fw2.y + pacc[2]*fw2.z + pacc[3]*fw2.w;
    float s3 = pacc[0]*fw3.x + pacc[1]*fw3.y + pacc[2]*fw3.z + pacc[3]*fw3.w;
    #pragma unroll
    for (int off=32; off; off>>=1){
      s0 += __shfl_xor(s0, off); s1 += __shfl_xor(s1, off);
      s2 += __shfl_xor(s2, off); s3 += __shfl_xor(s3, off);
    }
    if (lane < 4){
      const float s = (lane==0)?s0:(lane==1)?s1:(lane==2)?s2:s3;
      qin[(size_t)b*4 + lane] =
          tanhf(s*(1.f/36.f) + fcbg[lane]) * 3.14159265358979323846f;
    }
  }
}

// ---------------------------------------------------------------------------
// Kernel B: per-thread 4-qubit statevector sim + classifier head.
// wire w <-> bit mask (8 >> w)
// ---------------------------------------------------------------------------
template<int M>
__device__ __forceinline__ void g_ry(float* re, float* im, float c, float s){
  #pragma unroll
  for (int i=0;i<16;++i){
    if ((i & M)==0){
      const int j = i | M;
      const float r0=re[i], r1=re[j], q0=im[i], q1=im[j];
      re[i]=c*r0 - s*r1; re[j]=s*r0 + c*r1;
      im[i]=c*q0 - s*q1; im[j]=s*q0 + c*q1;
    }
  }
}
template<int M>
__device__ __forceinline__ void g_rz(float* re, float* im, float c, float s){
  #pragma unroll
  for (int i=0;i<16;++i){
    const float r=re[i], q=im[i];
    if ((i & M)==0){ re[i]=c*r + s*q; im[i]=c*q - s*r; }
    else           { re[i]=c*r - s*q; im[i]=c*q + s*r; }
  }
}
template<int CM,int TM>
__device__ __forceinline__ void g_cnot(float* re, float* im){
  #pragma unroll
  for (int i=0;i<16;++i){
    if ((i & CM) && !(i & TM)){
      const int j = i | TM;
      float t=re[i]; re[i]=re[j]; re[j]=t;
      t=im[i]; im[i]=im[j]; im[j]=t;
    }
  }
}

__global__ __launch_bounds__(256) void quantum_kernel(
    const float* __restrict__ qin, const float* __restrict__ qwg,
    const float* __restrict__ c1wg, const float* __restrict__ c1bg,
    const float* __restrict__ c2wg, const float* __restrict__ c2bg,
    float* __restrict__ out, int B)
{
  __shared__ float qc[32], qs[32], w1s[128], b1s[32], w2s[320], b2s[16];
  const int tid = threadIdx.x;
  if (tid < 32){ const float a = qwg[tid]*0.5f; qc[tid]=cosf(a); qs[tid]=sinf(a); }
  if (tid < 128) w1s[tid] = c1wg[tid];
  if (tid < 32)  b1s[tid] = c1bg[tid];
  for (int i=tid; i<320; i+=256) w2s[i] = c2wg[i];
  if (tid < 10)  b2s[tid] = c2bg[tid];
  __syncthreads();

  const int b = blockIdx.x*256 + tid;
  if (b >= B) return;

  const float4 ang = *(const float4*)(qin + (size_t)b*4);

  float re[16], im[16];
  #pragma unroll
  for (int i=0;i<16;++i){ re[i]=0.f; im[i]=0.f; }
  re[0] = 1.f;

  {
    float c,s;
    sincosf(ang.x*0.5f, &s, &c); g_ry<8>(re,im,c,s);
    sincosf(ang.y*0.5f, &s, &c); g_ry<4>(re,im,c,s);
    sincosf(ang.z*0.5f, &s, &c); g_ry<2>(re,im,c,s);
    sincosf(ang.w*0.5f, &s, &c); g_ry<1>(re,im,c,s);
  }

  #pragma unroll
  for (int l=0; l<4; ++l){
    const int o = l*8;
    g_ry<8>(re,im,qc[o+0],qs[o+0]);  g_rz<8>(re,im,qc[o+1],qs[o+1]);
    g_ry<4>(re,im,qc[o+2],qs[o+2]);  g_rz<4>(re,im,qc[o+3],qs[o+3]);
    g_ry<2>(re,im,qc[o+4],qs[o+4]);  g_rz<2>(re,im,qc[o+5],qs[o+5]);
    g_ry<1>(re,im,qc[o+6],qs[o+6]);  g_rz<1>(re,im,qc[o+7],qs[o+7]);
    g_cnot<8,4>(re,im); g_cnot<4,2>(re,im); g_cnot<2,1>(re,im); g_cnot<1,8>(re,im);
  }

  float p[16];
  #pragma unroll
  for (int i=0;i<16;++i) p[i] = re[i]*re[i] + im[i]*im[i];
  float z0=0.f, z1=0.f, z2=0.f, z3=0.f;
  #pragma unroll
  for (int i=0;i<16;++i){
    z0 += (i & 8) ? -p[i] : p[i];
    z1 += (i & 4) ? -p[i] : p[i];
    z2 += (i & 2) ? -p[i] : p[i];
    z3 += (i & 1) ? -p[i] : p[i];
  }

  float h[32];
  #pragma unroll
  for (int o=0;o<32;++o){
    const float v = b1s[o] + z0*w1s[o*4+0] + z1*w1s[o*4+1]
                           + z2*w1s[o*4+2] + z3*w1s[o*4+3];
    h[o] = fmaxf(v, 0.f);
  }
  #pragma unroll
  for (int o=0;o<10;++o){
    float v = b2s[o];
    #pragma unroll
    for (int k=0;k<32;++k) v += h[k]*w2s[o*32+k];
    out[(size_t)b*10 + o] = v;
  }
}

// ---------------------------------------------------------------------------
extern "C" void kernel_launch(void* const* d_in, const int* in_sizes, int n_in,
                              void* d_out, int out_size, void* d_ws, size_t ws_size,
                              hipStream_t stream)
{
  const float* x   = (const float*)d_in[0];
  const float* w1  = (const float*)d_in[1];
  const float* b1  = (const float*)d_in[2];
  const float* w2  = (const float*)d_in[3];
  const float* b2  = (const float*)d_in[4];
  const float* w3  = (const float*)d_in[5];
  const float* b3  = (const float*)d_in[6];
  const float* fcw = (const float*)d_in[7];
  const float* fcb = (const float*)d_in[8];
  const float* qw  = (const float*)d_in[9];
  const float* c1w = (const float*)d_in[10];
  const float* c1b = (const float*)d_in[11];
  const float* c2w = (const float*)d_in[12];
  const float* c2b = (const float*)d_in[13];
  float* outp = (float*)d_out;

  const int B = in_sizes[0] / 784;
  f16*   wsw = (f16*)d_ws;
  float* qin = (float*)((char*)d_ws + WS_QIN_OFF);

  precompute_weights<<<1, 256, 0, stream>>>(w1, w2, w3, wsw);

  classical_kernel<<<(B+3)/4, 256, 0, stream>>>(x, b1, b2, b3, fcw, fcb,
                                                wsw, qin, B);

  quantum_kernel<<<(B+255)/256, 256, 0, stream>>>(qin, qw, c1w, c1b,
                                                  c2w, c2b, outp, B);
}

// Round 7
// 79.335 us; speedup vs baseline: 10.4537x; 1.0915x over previous
//
#include <hip/hip_runtime.h>
#include <math.h>

typedef _Float16 f16;
typedef _Float16 f16x8 __attribute__((ext_vector_type(8)));
typedef float f32x4 __attribute__((ext_vector_type(4)));

// workspace: [0,16384) staged f16 weights; [16384, +B*16) qin
#define WS_QIN_OFF 16384
#define OW1   0      // [16][32] conv1 [oc][k] k=gk*8+ii: gk=ky, ii=1..3 -> kx=ii-1
#define OW2   512    // [16][96] conv2 [oc][pos12][ic8], pos>=9 zero
#define OW3   2048   // [16][160] conv3 [oc][k], k=pos*16+ic, pos>=9 zero
#define OPOOL 4608   // [16][64] 36x pool matrix (entries 9/6/4 exact f16)

// wave-internal fence: drain this wave's LDS/VMEM so cross-lane RAW is safe
// without a block barrier (each wave owns its LDS region).
__device__ __forceinline__ void wfence(){
  __builtin_amdgcn_sched_barrier(0);
  asm volatile("s_waitcnt vmcnt(0) lgkmcnt(0)" ::: "memory");
  __builtin_amdgcn_sched_barrier(0);
}

// ---------------------------------------------------------------------------
__global__ void precompute_weights(const float* __restrict__ w1g,
                                   const float* __restrict__ w2g,
                                   const float* __restrict__ w3g,
                                   f16* __restrict__ wsw){
  const int tid = threadIdx.x;
  // conv1 weights (R4-proven): rows oc<8, chunk gk=ky, ii=0 is the kx=-1
  // garbage slot (zero weight), ii=1..3 -> kx=ii-1, ii>=4 zero.
  for (int i=tid; i<512; i+=256){
    int oc = i >> 5, k = i & 31, gk = k >> 3, ii = k & 7;
    float v = 0.f;
    if (oc < 8 && gk < 3 && ii >= 1 && ii <= 3) v = w1g[oc*9 + gk*3 + (ii-1)];
    wsw[OW1 + i] = (f16)v;
  }
  for (int i=tid; i<1536; i+=256){
    int oc = i/96, r = i%96, p = r>>3, ic = r&7;
    wsw[OW2 + i] = (f16)(p < 9 ? w2g[oc*72 + ic*9 + p] : 0.f);
  }
  for (int i=tid; i<2560; i+=256){
    int oc = i/160, k = i%160, pos = k>>4, ic = k&15;
    wsw[OW3 + i] = (f16)(pos < 9 ? w3g[oc*144 + ic*9 + pos] : 0.f);
  }
  // 36x adaptive-pool matrix: P36[pq][pix], exact {9,6,4} in f16
  for (int i=tid; i<1024; i+=256){
    int pq = i >> 6, pix = i & 63;
    float v = 0.f;
    if (pix < 49){
      int p = pq >> 2, q = pq & 3, ii = pix/7, jj = pix%7;
      int sp = (p*7) >> 2, ep = (7*(p+1)+3) >> 2;
      int sq = (q*7) >> 2, eq = (7*(q+1)+3) >> 2;
      if (ii >= sp && ii < ep && jj >= sq && jj < eq)
        v = 36.f / (float)((ep-sp)*(eq-sq));
    }
    wsw[OPOOL + i] = (f16)v;
  }
}

// ---------------------------------------------------------------------------
// One WAVE per sample, 4 waves/block, zero block barriers. All MFMA operands
// indexed with kappa(g,i)=g*8+i on both operands (HW k-perm cancels;
// validated R2-R6). D-mapping (pinned R2 conv2 + R4 conv3): D rows <- arg0's
// per-lane index, D cols <- arg1's; lane (l15,g) reg j holds D[g*4+j][l15].
// Garbage-tolerance rules used for border-only zeroing:
//   A[m][k] garbage (even NaN) -> only D row m;  B[k][n] garbage -> only
//   D col n;  any k-slot with NONZERO weight must be real/zero-pad; k-slots
//   with zero weight need only FINITE data (we zero or own-write them).
// ---------------------------------------------------------------------------
__global__ __launch_bounds__(256, 4) void classical_kernel(
    const float* __restrict__ xg,
    const float* __restrict__ b1g, const float* __restrict__ b2g,
    const float* __restrict__ b3g,
    const float* __restrict__ fcwg, const float* __restrict__ fcbg,
    const f16* __restrict__ wsw, float* __restrict__ qin, int B)
{
  // per-wave 7984B: region A [0,3888)    = xs [30][36] f16, later c2ps [81][24]
  //                 region B [3888,7984) = c1s [16][16][8] f16, later c3t [16][72]
  __shared__ __align__(16) unsigned char pw[4][7984];

  const int tid = threadIdx.x, lane = tid & 63, wv = tid >> 6;
  const int l15 = lane & 15, g = lane >> 4;

  const int b = blockIdx.x*4 + wv;
  if (b >= B) return;

  f16* xs   = (f16*)&pw[wv][0];       // [30][36], col = x_img+4, row = y_img+1
  f16* c2ps = xs;                     // overlay: [81 pos][24 ch]
  f16* c1s  = (f16*)&pw[wv][3888];    // [16 row][16 col][8 ic] = 4096B exactly
  f16* c3t  = c1s;                    // overlay: [16 oc][72 pix] (144B rows)

  // ---- border-only zero: xs rows 0,29 + cols 2,3 (rows 1..28) = 64 u32 ----
  {
    unsigned* pz = (unsigned*)xs;     // rows of 18 dw
    int dw;
    if (lane < 18)      dw = lane;                      // row 0
    else if (lane < 36) dw = 29*18 + (lane - 18);       // row 29
    else                dw = (lane - 35)*18 + 1;        // rows 1..28, f16 cols 2,3
    pz[dw] = 0u;
  }
  // ---- border-only zero: c1s rows 0,15 + cols 0,15 (60 b128) ----
  {
    const f32x4 z4 = {0.f,0.f,0.f,0.f};
    f32x4* pz = (f32x4*)c1s;          // b128 idx = row*16 + col
    if (lane < 60){
      int dst;
      if (lane < 16)      dst = lane;                   // row 0
      else if (lane < 32) dst = 15*16 + (lane - 16);    // row 15
      else if (lane < 46) dst = (lane - 31)*16;         // col 0, rows 1..14
      else                dst = (lane - 45)*16 + 15;    // col 15, rows 1..14
      pz[dst] = z4;
    }
  }

  // ---- stage input: float4 global -> 4xf16 b64 LDS ----
  {
    const float4* xg4 = (const float4*)(xg + (size_t)b*784);
    #pragma unroll
    for (int r=0; r<4; ++r){
      const int idx = r*64 + lane;
      if (idx < 196){
        float4 v = xg4[idx];
        int y = idx/7, xq = idx - y*7;
        union { f16 h[4]; unsigned long long u; } pk;
        pk.h[0]=(f16)v.x; pk.h[1]=(f16)v.y; pk.h[2]=(f16)v.z; pk.h[3]=(f16)v.w;
        *(unsigned long long*)&xs[(y+1)*36 + xq*4 + 4] = pk.u;
      }
    }
  }
  wfence();

  // ---- conv1 (1->8, stride2, pad1) + relu via MFMA (R4-proven form) ----
  // A=weights (rows oc), B=image: chunk g = ky (g=3 all-zero weights), taps
  // i=0 -> kx=-1 (zero wt), i=1..3 -> kx=i-1, i>=4 zeroed in-reg.
  // D[oc=g*4+j][x=l15], write b64 (4 ic).
  {
    const f16x8 aw = *(const f16x8*)&wsw[OW1 + l15*32 + g*8];
    const float4 bv = ((const float4*)b1g)[g & 1];   // oc g*4..g*4+3 (g<2)
    const unsigned* xsw = (const unsigned*)xs;       // u32 rows of 18
    for (int oy=0; oy<14; ++oy){
      const int bu = (2*oy + g)*18 + l15 + 1;        // f16 col 2*l15+2
      union { unsigned u[4]; f16x8 v; } bf;
      bf.u[0] = xsw[bu];
      bf.u[1] = xsw[bu+1];
      bf.u[2] = 0u; bf.u[3] = 0u;
      f32x4 acc = {0.f,0.f,0.f,0.f};
      acc = __builtin_amdgcn_mfma_f32_16x16x32_f16(aw, bf.v, acc, 0,0,0);
      if (g < 2 && l15 < 14){
        union { f16 h[4]; unsigned long long u; } pk;
        #pragma unroll
        for (int j=0;j<4;++j) pk.h[j] = (f16)fmaxf(acc[j] + bv[j], 0.f);
        *(unsigned long long*)&c1s[((oy+1)*16 + (l15+1))*8 + g*4] = pk.u;
      }
    }
  }
  wfence();

  // ---- conv2 (8->16, pad1) + maxpool2 + bias + relu via MFMA ----
  // A=image (m=x), B=weights (n=oc); pool folds in-register.
  // c1s cols 16,17 overflow-reads only enter A rows m=14,15 -> D rows
  // discarded; OOB-LDS reads return 0/garbage, both tolerated.
  {
    const f16x8 bf0 = *(const f16x8*)&wsw[OW2 + l15*96      + g*8];
    const f16x8 bf1 = *(const f16x8*)&wsw[OW2 + l15*96 + 32 + g*8];
    const f16x8 bf2 = *(const f16x8*)&wsw[OW2 + l15*96 + 64 + g*8];
    const float bias2 = b2g[l15];
    // border-only zero of c2ps (overlays dead xs): unwritten indices are
    // rows 0,8 and cols 0,8 of the 9x9 -> bulks 0..9, 71..80 + 6 pairs.
    {
      const f32x4 z4 = {0.f,0.f,0.f,0.f};
      f32x4* pz = (f32x4*)c2ps;
      for (int i=lane; i<96; i+=64){
        int dst;
        if (i < 30)      dst = i;                       // idx 0..9   (480B)
        else if (i < 60) dst = 213 + (i - 30);          // idx 71..80 (480B)
        else { int j = (i-60)/6, s = (i-60)%6; dst = (17 + 9*j)*3 + s; }
        pz[dst] = z4;
      }
    }
    const int p0 = g,     r0o = p0/3, c0o = p0%3;
    const int p1 = 4 + g, r1o = p1/3, c1o = p1%3;
    float hA = 0.f, hB = 0.f;
    for (int y=0; y<14; ++y){
      f16x8 a0 = *(const f16x8*)&c1s[((y + r0o)*16 + l15 + c0o)*8];
      f16x8 a1 = *(const f16x8*)&c1s[((y + r1o)*16 + l15 + c1o)*8];
      f16x8 a2 = *(const f16x8*)&c1s[((y + 2  )*16 + l15 + 2  )*8];
      f32x4 acc = {0.f,0.f,0.f,0.f};
      acc = __builtin_amdgcn_mfma_f32_16x16x32_f16(a0, bf0, acc, 0,0,0);
      acc = __builtin_amdgcn_mfma_f32_16x16x32_f16(a1, bf1, acc, 0,0,0);
      acc = __builtin_amdgcn_mfma_f32_16x16x32_f16(a2, bf2, acc, 0,0,0);
      const float m0 = fmaxf(acc[0], acc[1]);   // x = 4g,4g+1   -> px=2g
      const float m1 = fmaxf(acc[2], acc[3]);   // x = 4g+2,4g+3 -> px=2g+1
      if ((y & 1) == 0){ hA = m0; hB = m1; }
      else {
        const int py = y >> 1;
        const float vA = fmaxf(fmaxf(hA, m0) + bias2, 0.f);
        const float vB = fmaxf(fmaxf(hB, m1) + bias2, 0.f);
        c2ps[((py+1)*9 + (2*g+1))*24 + l15] = (f16)vA;        // px=2g
        if (g < 3)
          c2ps[((py+1)*9 + (2*g+2))*24 + l15] = (f16)vB;      // px=2g+1
      }
    }
  }
  wfence();

  // ---- conv3 (16->16, pad1) + bias + relu : A=image, B=weights ----
  // D[m=pix-in-tile=g*4+j][n=oc=l15]; store c3t[oc=l15][pix], b64.
  // Tile3 pix 49..63 are clamped duplicates of pix 48 (finite), zero pool wt.
  {
    f16x8 cf[5];
    #pragma unroll
    for (int kk=0; kk<5; ++kk)
      cf[kk] = *(const f16x8*)&wsw[OW3 + l15*160 + kk*32 + g*8];
    const float bias3 = b3g[l15];
    const int gh = g >> 1, icb = (g & 1)*8;
    #pragma unroll
    for (int tile=0; tile<4; ++tile){
      unsigned m = (unsigned)(tile*16 + l15); if (m > 48u) m = 48u;
      const int rcb = (int)(m/7u)*9 + (int)(m%7u);
      f32x4 acc = {0.f,0.f,0.f,0.f};
      #pragma unroll
      for (int kk=0; kk<5; ++kk){
        int p = 2*kk + gh; if (p > 8) p = 8;      // weight rows pos>=9 zero
        f16x8 a = *(const f16x8*)&c2ps[(rcb + (p/3)*9 + (p%3))*24 + icb];
        acc = __builtin_amdgcn_mfma_f32_16x16x32_f16(a, cf[kk], acc, 0,0,0);
      }
      union { f16 h[4]; unsigned long long u; } pk;
      #pragma unroll
      for (int j=0;j<4;++j) pk.h[j] = (f16)fmaxf(acc[j] + bias3, 0.f);
      *(unsigned long long*)&c3t[l15*72 + tile*16 + g*4] = pk.u;
    }
  }
  wfence();

  // ---- adaptive pool as 2 MFMAs: D[m=pq][n=oc] = 36*feat[oc][pq] ----
  // A=P36 (arg0, rows pq), B=c3t (arg1, cols oc). Lane reg j holds
  // 36*feat[oc=l15][pq=g*4+j] -> flatten t = l15*16 + g*4 + j.
  f32x4 pacc = {0.f,0.f,0.f,0.f};
  {
    const f16x8 pA0 = *(const f16x8*)&wsw[OPOOL + l15*64      + g*8];
    const f16x8 pA1 = *(const f16x8*)&wsw[OPOOL + l15*64 + 32 + g*8];
    const f16x8 pB0 = *(const f16x8*)&c3t[l15*72      + g*8];
    const f16x8 pB1 = *(const f16x8*)&c3t[l15*72 + 32 + g*8];
    pacc = __builtin_amdgcn_mfma_f32_16x16x32_f16(pA0, pB0, pacc, 0,0,0);
    pacc = __builtin_amdgcn_mfma_f32_16x16x32_f16(pA1, pB1, pacc, 0,0,0);
  }

  // ---- fc (256->4) + tanh*pi : shfl_xor butterfly (R3/R6-proven) ----
  {
    const float4 fw0 = *(const float4*)&fcwg[      l15*16 + g*4];
    const float4 fw1 = *(const float4*)&fcwg[256 + l15*16 + g*4];
    const float4 fw2 = *(const float4*)&fcwg[512 + l15*16 + g*4];
    const float4 fw3 = *(const float4*)&fcwg[768 + l15*16 + g*4];
    float s0 = pacc[0]*fw0.x + pacc[1]*fw0.y + pacc[2]*fw0.z + pacc[3]*fw0.w;
    float s1 = pacc[0]*fw1.x + pacc[1]*fw1.y + pacc[2]*fw1.z + pacc[3]*fw1.w;
    float s2 = pacc[0]*fw2.x + pacc[1]*fw2.y + pacc[2]*fw2.z + pacc[3]*fw2.w;
    float s3 = pacc[0]*fw3.x + pacc[1]*fw3.y + pacc[2]*fw3.z + pacc[3]*fw3.w;
    #pragma unroll
    for (int off=32; off; off>>=1){
      s0 += __shfl_xor(s0, off); s1 += __shfl_xor(s1, off);
      s2 += __shfl_xor(s2, off); s3 += __shfl_xor(s3, off);
    }
    if (lane < 4){
      const float s = (lane==0)?s0:(lane==1)?s1:(lane==2)?s2:s3;
      qin[(size_t)b*4 + lane] =
          tanhf(s*(1.f/36.f) + fcbg[lane]) * 3.14159265358979323846f;
    }
  }
}

// ---------------------------------------------------------------------------
// Kernel B: per-thread 4-qubit statevector sim + classifier head.
// wire w <-> bit mask (8 >> w)
// ---------------------------------------------------------------------------
template<int M>
__device__ __forceinline__ void g_ry(float* re, float* im, float c, float s){
  #pragma unroll
  for (int i=0;i<16;++i){
    if ((i & M)==0){
      const int j = i | M;
      const float r0=re[i], r1=re[j], q0=im[i], q1=im[j];
      re[i]=c*r0 - s*r1; re[j]=s*r0 + c*r1;
      im[i]=c*q0 - s*q1; im[j]=s*q0 + c*q1;
    }
  }
}
template<int M>
__device__ __forceinline__ void g_rz(float* re, float* im, float c, float s){
  #pragma unroll
  for (int i=0;i<16;++i){
    const float r=re[i], q=im[i];
    if ((i & M)==0){ re[i]=c*r + s*q; im[i]=c*q - s*r; }
    else           { re[i]=c*r - s*q; im[i]=c*q + s*r; }
  }
}
template<int CM,int TM>
__device__ __forceinline__ void g_cnot(float* re, float* im){
  #pragma unroll
  for (int i=0;i<16;++i){
    if ((i & CM) && !(i & TM)){
      const int j = i | TM;
      float t=re[i]; re[i]=re[j]; re[j]=t;
      t=im[i]; im[i]=im[j]; im[j]=t;
    }
  }
}

__global__ __launch_bounds__(256) void quantum_kernel(
    const float* __restrict__ qin, const float* __restrict__ qwg,
    const float* __restrict__ c1wg, const float* __restrict__ c1bg,
    const float* __restrict__ c2wg, const float* __restrict__ c2bg,
    float* __restrict__ out, int B)
{
  __shared__ float qc[32], qs[32], w1s[128], b1s[32], w2s[320], b2s[16];
  const int tid = threadIdx.x;
  if (tid < 32){ const float a = qwg[tid]*0.5f; qc[tid]=cosf(a); qs[tid]=sinf(a); }
  if (tid < 128) w1s[tid] = c1wg[tid];
  if (tid < 32)  b1s[tid] = c1bg[tid];
  for (int i=tid; i<320; i+=256) w2s[i] = c2wg[i];
  if (tid < 10)  b2s[tid] = c2bg[tid];
  __syncthreads();

  const int b = blockIdx.x*256 + tid;
  if (b >= B) return;

  const float4 ang = *(const float4*)(qin + (size_t)b*4);

  float re[16], im[16];
  #pragma unroll
  for (int i=0;i<16;++i){ re[i]=0.f; im[i]=0.f; }
  re[0] = 1.f;

  {
    float c,s;
    sincosf(ang.x*0.5f, &s, &c); g_ry<8>(re,im,c,s);
    sincosf(ang.y*0.5f, &s, &c); g_ry<4>(re,im,c,s);
    sincosf(ang.z*0.5f, &s, &c); g_ry<2>(re,im,c,s);
    sincosf(ang.w*0.5f, &s, &c); g_ry<1>(re,im,c,s);
  }

  #pragma unroll
  for (int l=0; l<4; ++l){
    const int o = l*8;
    g_ry<8>(re,im,qc[o+0],qs[o+0]);  g_rz<8>(re,im,qc[o+1],qs[o+1]);
    g_ry<4>(re,im,qc[o+2],qs[o+2]);  g_rz<4>(re,im,qc[o+3],qs[o+3]);
    g_ry<2>(re,im,qc[o+4],qs[o+4]);  g_rz<2>(re,im,qc[o+5],qs[o+5]);
    g_ry<1>(re,im,qc[o+6],qs[o+6]);  g_rz<1>(re,im,qc[o+7],qs[o+7]);
    g_cnot<8,4>(re,im); g_cnot<4,2>(re,im); g_cnot<2,1>(re,im); g_cnot<1,8>(re,im);
  }

  float p[16];
  #pragma unroll
  for (int i=0;i<16;++i) p[i] = re[i]*re[i] + im[i]*im[i];
  float z0=0.f, z1=0.f, z2=0.f, z3=0.f;
  #pragma unroll
  for (int i=0;i<16;++i){
    z0 += (i & 8) ? -p[i] : p[i];
    z1 += (i & 4) ? -p[i] : p[i];
    z2 += (i & 2) ? -p[i] : p[i];
    z3 += (i & 1) ? -p[i] : p[i];
  }

  float h[32];
  #pragma unroll
  for (int o=0;o<32;++o){
    const float v = b1s[o] + z0*w1s[o*4+0] + z1*w1s[o*4+1]
                           + z2*w1s[o*4+2] + z3*w1s[o*4+3];
    h[o] = fmaxf(v, 0.f);
  }
  #pragma unroll
  for (int o=0;o<10;++o){
    float v = b2s[o];
    #pragma unroll
    for (int k=0;k<32;++k) v += h[k]*w2s[o*32+k];
    out[(size_t)b*10 + o] = v;
  }
}

// ---------------------------------------------------------------------------
extern "C" void kernel_launch(void* const* d_in, const int* in_sizes, int n_in,
                              void* d_out, int out_size, void* d_ws, size_t ws_size,
                              hipStream_t stream)
{
  const float* x   = (const float*)d_in[0];
  const float* w1  = (const float*)d_in[1];
  const float* b1  = (const float*)d_in[2];
  const float* w2  = (const float*)d_in[3];
  const float* b2  = (const float*)d_in[4];
  const float* w3  = (const float*)d_in[5];
  const float* b3  = (const float*)d_in[6];
  const float* fcw = (const float*)d_in[7];
  const float* fcb = (const float*)d_in[8];
  const float* qw  = (const float*)d_in[9];
  const float* c1w = (const float*)d_in[10];
  const float* c1b = (const float*)d_in[11];
  const float* c2w = (const float*)d_in[12];
  const float* c2b = (const float*)d_in[13];
  float* outp = (float*)d_out;

  const int B = in_sizes[0] / 784;
  f16*   wsw = (f16*)d_ws;
  float* qin = (float*)((char*)d_ws + WS_QIN_OFF);

  precompute_weights<<<1, 256, 0, stream>>>(w1, w2, w3, wsw);

  classical_kernel<<<(B+3)/4, 256, 0, stream>>>(x, b1, b2, b3, fcw, fcb,
                                                wsw, qin, B);

  quantum_kernel<<<(B+255)/256, 256, 0, stream>>>(qin, qw, c1w, c1b,
                                                  c2w, c2b, outp, B);
}